// Round 13
// baseline (668.880 us; speedup 1.0000x reference)
//
#include <hip/hip_runtime.h>
#include <hip/hip_bf16.h>

// Problem constants
#define B_  2
#define S_  2048
#define D_  4096
#define H_  32
#define KVH_ 8
#define HD_ 128
#define WIN_ 1024
#define KVSTR 2048   // merged KV row stride (K cols 0-1023, V cols 1024-2047)

typedef __attribute__((ext_vector_type(8))) __bf16 bf16x8;
typedef __attribute__((ext_vector_type(4))) float f32x4;
using bf16 = __hip_bfloat16;

typedef const __attribute__((address_space(1))) void* gas_ptr;
typedef __attribute__((address_space(3))) void* las_ptr;

// async global->LDS, 16B per lane; lds dest = (wave-uniform) l + lane*16
__device__ __forceinline__ void gload16(const void* g, void* l) {
    __builtin_amdgcn_global_load_lds((gas_ptr)g, (las_ptr)l, 16, 0, 0);
}

__device__ __forceinline__ bf16x8 load8(const bf16* p) {
    return *reinterpret_cast<const bf16x8*>(p);
}
__device__ __forceinline__ bf16x8 cvt8(const bf16* p) {
    return *reinterpret_cast<const bf16x8*>(p);
}
__device__ __forceinline__ bf16x8 cvt8(const float* p) {
    const float4* q = reinterpret_cast<const float4*>(p);
    float4 a = q[0], b = q[1];
    bf16x8 r;
    r[0] = (__bf16)a.x; r[1] = (__bf16)a.y; r[2] = (__bf16)a.z; r[3] = (__bf16)a.w;
    r[4] = (__bf16)b.x; r[5] = (__bf16)b.y; r[6] = (__bf16)b.z; r[7] = (__bf16)b.w;
    return r;
}
__device__ __forceinline__ void store1(float* p, float v) { *p = v; }
__device__ __forceinline__ void store1(bf16* p, float v) { *p = __float2bfloat16(v); }

#define GBAR()  __builtin_amdgcn_s_barrier()
#define SCB0()  __builtin_amdgcn_sched_barrier(0)
#define LGKM0() do { asm volatile("s_waitcnt lgkmcnt(0)" ::: "memory"); \
                     __builtin_amdgcn_sched_barrier(0); } while (0)
#define VMC(n)  do { asm volatile("s_waitcnt vmcnt(" #n ")" ::: "memory"); \
                     __builtin_amdgcn_sched_barrier(0); } while (0)

// ---------------------------------------------------------------------------
// f32 -> bf16 cast, 8 elements/thread, exact-size launch (n % 2048 == 0)
// ---------------------------------------------------------------------------
__global__ __launch_bounds__(256) void cast_kernel(const float* __restrict__ in,
                                                   bf16* __restrict__ out) {
    long i = ((long)blockIdx.x * 256 + threadIdx.x) * 8;
    const float4* p = reinterpret_cast<const float4*>(in + i);
    float4 a = p[0], b = p[1];
    bf16x8 r;
    r[0] = (__bf16)a.x; r[1] = (__bf16)a.y; r[2] = (__bf16)a.z; r[3] = (__bf16)a.w;
    r[4] = (__bf16)b.x; r[5] = (__bf16)b.y; r[6] = (__bf16)b.z; r[7] = (__bf16)b.w;
    *reinterpret_cast<bf16x8*>(out + i) = r;
}

// two casts in one launch: blocks [0,n0) -> pair0, rest -> pair1
__global__ __launch_bounds__(256) void cast2_kernel(
    const float* __restrict__ in0, bf16* __restrict__ out0,
    const float* __restrict__ in1, bf16* __restrict__ out1, int n0blocks) {
    const bool first = (int)blockIdx.x < n0blocks;
    const float* in = first ? in0 : in1;
    bf16* out = first ? out0 : out1;
    long bid = first ? blockIdx.x : (blockIdx.x - n0blocks);
    long i = (bid * 256 + threadIdx.x) * 8;
    const float4* p = reinterpret_cast<const float4*>(in + i);
    float4 a = p[0], b = p[1];
    bf16x8 r;
    r[0] = (__bf16)a.x; r[1] = (__bf16)a.y; r[2] = (__bf16)a.z; r[3] = (__bf16)a.w;
    r[4] = (__bf16)b.x; r[5] = (__bf16)b.y; r[6] = (__bf16)b.z; r[7] = (__bf16)b.w;
    *reinterpret_cast<bf16x8*>(out + i) = r;
}

// T1 XCD swizzle: requires nwg % 8 == 0 (all our grids: 256, 512).
__device__ __forceinline__ void xcd_swizzle(int& bx, int& by, int nbx, int nby) {
    int flat = bx + nbx * by;
    int nwg  = nbx * nby;
    int cpx  = nwg >> 3;
    int swz  = (flat & 7) * cpx + (flat >> 3);
    bx = swz % nbx;
    by = swz / nbx;
}

// ---------------------------------------------------------------------------
// 256x256 deep-pipelined NT GEMM (bf16 in): C = A[M,K] @ B[N,K]^T.
// 8 waves (2Mx4N), BK=64, 2-deep LDS dbuf (128 KiB), 4 phases/K-tile.
// Counted vmcnt(6). NOTE: 128 KiB LDS -> 1 block/CU; grid must be <=256
// (round-11 lesson). [verified rounds 2/5/6/7/8/10/12]
// ---------------------------------------------------------------------------
template <typename TC>
__global__ __launch_bounds__(512, 2) void gemm_nt_256(
    const bf16* __restrict__ A, const bf16* __restrict__ Bm,
    TC* __restrict__ C, int M, int N, int K) {
    // [buf][0=A,1=B][256 rows x 64 cols]
    __shared__ __bf16 lds[2][2][256 * 64];   // 128 KiB

    const int tid  = threadIdx.x;
    const int wave = tid >> 6;          // 0..7
    const int lane = tid & 63;
    const int col  = lane & 15;
    const int quad = lane >> 4;
    const int c7   = col & 7;
    const int wmi  = wave >> 2;         // 0..1  (M half)
    const int wni  = wave & 3;          // 0..3  (N quarter)
    int bx = blockIdx.x, by = blockIdx.y;
    xcd_swizzle(bx, by, gridDim.x, gridDim.y);
    const long m0  = (long)by * 256;
    const long n0  = (long)bx * 256;
    const int  nt  = K >> 6;            // K-tiles

    f32x4 zero = {0.f, 0.f, 0.f, 0.f};
    f32x4 acc[8][4];
#pragma unroll
    for (int i = 0; i < 8; i++)
#pragma unroll
        for (int j = 0; j < 4; j++) acc[i][j] = zero;

    // staging: load j covers rows j*64 + wave*8 .. +7 (this wave's slice)
    long gA[4], gB[4];
    int  lofs[4];
#pragma unroll
    for (int j = 0; j < 4; j++) {
        int r  = j * 64 + wave * 8 + (lane >> 3);
        int cg = (lane & 7) ^ (r & 7);          // pre-swizzled source chunk
        gA[j]   = (m0 + r) * (long)K + cg * 8;
        gB[j]   = (n0 + r) * (long)K + cg * 8;
        lofs[j] = (j * 64 + wave * 8) * 128;    // bytes; HW adds lane*16
    }

    // ---- prologue: tile0 full (8) + tile1 B(4)+A-lo(2) = 14 loads ----
#pragma unroll
    for (int j = 0; j < 4; j++) {
        gload16(A  + gA[j], (char*)lds[0][0] + lofs[j]);
        gload16(Bm + gB[j], (char*)lds[0][1] + lofs[j]);
    }
    if (nt > 1) {
#pragma unroll
        for (int j = 0; j < 4; j++)
            gload16(Bm + gB[j] + 64, (char*)lds[1][1] + lofs[j]);
        gload16(A + gA[0] + 64, (char*)lds[1][0] + lofs[0]);
        gload16(A + gA[2] + 64, (char*)lds[1][0] + lofs[2]);
        VMC(6);
    } else {
        VMC(0);
    }
    GBAR();

#define RDA_(dst, mf, ks) \
    dst = *reinterpret_cast<const bf16x8*>(Ab + (wmi * 128 + (mf) * 16 + col) * 128 \
                                              + ((((ks) << 2) + quad) ^ c7) * 16)
#define MFMA16(mb) \
    do { \
        _Pragma("unroll") \
        for (int ks = 0; ks < 2; ks++) { \
            _Pragma("unroll") \
            for (int nf = 0; nf < 4; nf++) { \
                acc[mb][nf]     = __builtin_amdgcn_mfma_f32_16x16x32_bf16( \
                    a[0][ks], bfr[nf][ks], acc[mb][nf], 0, 0, 0); \
                acc[mb + 1][nf] = __builtin_amdgcn_mfma_f32_16x16x32_bf16( \
                    a[1][ks], bfr[nf][ks], acc[mb + 1][nf], 0, 0, 0); \
            } \
        } \
    } while (0)

    for (int t = 0; t < nt; ++t) {
        const int cur = t & 1;
        const char* Ab = (const char*)lds[cur][0];
        const char* Bb = (const char*)lds[cur][1];
        char* An2 = (char*)lds[cur ^ 1][0];   // tile t+1 A (finish hi rows)
        char* Ac2 = (char*)lds[cur][0];       // tile t+2 A (parity == t)
        char* Bc2 = (char*)lds[cur][1];       // tile t+2 B

        // ---------------- P1 ----------------
        bf16x8 bfr[4][2];
#pragma unroll
        for (int nf = 0; nf < 4; nf++)
#pragma unroll
            for (int ks = 0; ks < 2; ks++)
                bfr[nf][ks] = *reinterpret_cast<const bf16x8*>(
                    Bb + (wni * 64 + nf * 16 + col) * 128 + (((ks << 2) + quad) ^ c7) * 16);
        bf16x8 a[2][2];
        RDA_(a[0][0], 0, 0); RDA_(a[0][1], 0, 1);
        RDA_(a[1][0], 1, 0); RDA_(a[1][1], 1, 1);
        if (t + 1 < nt) {                      // stage A hi-rows of tile t+1
            long ko = (long)(t + 1) * 64;
            gload16(A + gA[1] + ko, An2 + lofs[1]);
            gload16(A + gA[3] + ko, An2 + lofs[3]);
        }
        GBAR();
        LGKM0();
        __builtin_amdgcn_s_setprio(1);
        MFMA16(0);
        __builtin_amdgcn_s_setprio(0);
        GBAR();

        // ---------------- P2 ----------------
        RDA_(a[0][0], 2, 0); RDA_(a[0][1], 2, 1);
        RDA_(a[1][0], 3, 0); RDA_(a[1][1], 3, 1);
        if (t + 2 < nt) {                      // stage B of tile t+2
            long ko = (long)(t + 2) * 64;
#pragma unroll
            for (int j = 0; j < 4; j++)
                gload16(Bm + gB[j] + ko, Bc2 + lofs[j]);
        }
        GBAR();
        LGKM0();
        __builtin_amdgcn_s_setprio(1);
        MFMA16(2);
        __builtin_amdgcn_s_setprio(0);
        GBAR();

        // ---------------- P3 ----------------
        RDA_(a[0][0], 4, 0); RDA_(a[0][1], 4, 1);
        RDA_(a[1][0], 5, 0); RDA_(a[1][1], 5, 1);
        if (t + 2 < nt) {                      // stage A lo-rows of tile t+2
            long ko = (long)(t + 2) * 64;
            gload16(A + gA[0] + ko, Ac2 + lofs[0]);
            gload16(A + gA[2] + ko, Ac2 + lofs[2]);
        }
        GBAR();
        LGKM0();
        __builtin_amdgcn_s_setprio(1);
        MFMA16(4);
        __builtin_amdgcn_s_setprio(0);
        GBAR();

        // ---------------- P4 ----------------
        RDA_(a[0][0], 6, 0); RDA_(a[0][1], 6, 1);
        RDA_(a[1][0], 7, 0); RDA_(a[1][1], 7, 1);
        LGKM0();
        __builtin_amdgcn_s_setprio(1);
        MFMA16(6);
        __builtin_amdgcn_s_setprio(0);
        if (t + 2 < nt) { VMC(6); } else { VMC(0); }
        GBAR();
    }

    // C/D layout: col=lane&15, row=quad*4+reg  [m89/m91 verified]
#pragma unroll
    for (int mf = 0; mf < 8; mf++) {
#pragma unroll
        for (int nf = 0; nf < 4; nf++) {
            long row = m0 + wmi * 128 + mf * 16 + quad * 4;
            long cc  = n0 + wni * 64 + nf * 16 + col;
#pragma unroll
            for (int r = 0; r < 4; r++)
                store1(&C[(row + r) * (long)N + cc], acc[mf][nf][r]);
        }
    }
}

// ---------------------------------------------------------------------------
// FAST NT GEMM + fused K-RoPE epilogue (bf16 out). 128x128 tile, BK=64.
// Used for the MERGED K+V projection (N=2048; K part = cols 0-1023).
// RoPE in epilogue: pair element lives in lane^1 (C/D layout col=lane&15),
// rotate in f32 BEFORE the only bf16 rounding (one fewer rounding than the
// separate rope pass). V part (cc>=1024) stored unmodified.
// ---------------------------------------------------------------------------
__global__ __launch_bounds__(256) void gemm_nt_fast_rope(
    const bf16* __restrict__ A, const bf16* __restrict__ Bm,
    bf16* __restrict__ C, int M, int N, int K,
    const float* __restrict__ cosb, const float* __restrict__ sinb) {
    __shared__ __bf16 As[128 * 64];   // 16 KB, swizzled, unpadded
    __shared__ __bf16 Bs[128 * 64];

    const int tid  = threadIdx.x;
    const int wave = tid >> 6;
    const int lane = tid & 63;
    const int col  = lane & 15;
    const int quad = lane >> 4;
    const int c7   = col & 7;
    const int wm   = (wave >> 1) * 64;
    const int wn   = (wave & 1) * 64;
    int bx = blockIdx.x, by = blockIdx.y;
    xcd_swizzle(bx, by, gridDim.x, gridDim.y);
    const long m0  = (long)by * 128;
    const long n0  = (long)bx * 128;

    f32x4 zero = {0.f, 0.f, 0.f, 0.f};
    f32x4 acc[4][4];
#pragma unroll
    for (int i = 0; i < 4; i++)
#pragma unroll
        for (int j = 0; j < 4; j++) acc[i][j] = zero;

    long goffA[4], goffB[4];
    int  loff[4];
#pragma unroll
    for (int i = 0; i < 4; i++) {
        int r  = (wave * 4 + i) * 8 + (lane >> 3);
        int cg = (lane & 7) ^ (r & 7);
        goffA[i] = (m0 + r) * (long)K + cg * 8;
        goffB[i] = (n0 + r) * (long)K + cg * 8;
        loff[i]  = (wave * 4 + i) * 1024;   // bytes; HW adds lane*16
    }

    for (int kt = 0; kt < K; kt += 64) {
#pragma unroll
        for (int i = 0; i < 4; i++) {
            gload16(A + goffA[i] + kt, (char*)As + loff[i]);
            gload16(Bm + goffB[i] + kt, (char*)Bs + loff[i]);
        }
        __syncthreads();

        bf16x8 af[2][4], bfv[2][4];
#pragma unroll
        for (int ks = 0; ks < 2; ks++) {
#pragma unroll
            for (int mt = 0; mt < 4; mt++) {
                int row = wm + mt * 16 + col;
                af[ks][mt] = *reinterpret_cast<const bf16x8*>(
                    (const char*)As + row * 128 + (((ks << 2) + quad) ^ c7) * 16);
            }
#pragma unroll
            for (int nt = 0; nt < 4; nt++) {
                int row = wn + nt * 16 + col;
                bfv[ks][nt] = *reinterpret_cast<const bf16x8*>(
                    (const char*)Bs + row * 128 + (((ks << 2) + quad) ^ c7) * 16);
            }
        }
#pragma unroll
        for (int ks = 0; ks < 2; ks++)
#pragma unroll
            for (int mt = 0; mt < 4; mt++)
#pragma unroll
                for (int nt = 0; nt < 4; nt++)
                    acc[mt][nt] = __builtin_amdgcn_mfma_f32_16x16x32_bf16(
                        af[ks][mt], bfv[ks][nt], acc[mt][nt], 0, 0, 0);
        __syncthreads();
    }

    // epilogue with fused K-RoPE (cc < 1024 only; uniform per nt since
    // nt-block base is a multiple of 16 and col < 16)
#pragma unroll
    for (int mt = 0; mt < 4; mt++) {
#pragma unroll
        for (int nt = 0; nt < 4; nt++) {
            long row = m0 + wm + mt * 16 + quad * 4;
            long cc  = n0 + wn + nt * 16 + col;
            const bool isK = cc < 1024;
            const int  p   = ((int)cc & 127) >> 1;   // pair index within head
            const bool odd = (cc & 1);
#pragma unroll
            for (int r = 0; r < 4; r++) {
                float v  = acc[mt][nt][r];
                float vp = __shfl_xor(v, 1, 64);     // pair element (lane^1)
                if (isK) {
                    int s = (int)((row + r) & (S_ - 1));
                    float c  = cosb[s * 64 + p];
                    float sn = sinb[s * 64 + p];
                    v = odd ? (vp * sn + v * c) : (v * c - vp * sn);
                }
                C[(row + r) * (long)N + cc] = __float2bfloat16(v);
            }
        }
    }
}

// ---------------------------------------------------------------------------
// SLOW NT GEMM (f32/bf16 in, convert at staging) — fallback if ws too small.
// ---------------------------------------------------------------------------
template <typename TA, typename TB, typename TC>
__global__ __launch_bounds__(256) void gemm_nt(
    const TA* __restrict__ A, const TB* __restrict__ Bm,
    TC* __restrict__ C, int M, int N, int K, int ldc) {
    __shared__ __bf16 As[128 * 40];
    __shared__ __bf16 Bs[128 * 40];

    const int tid  = threadIdx.x;
    const int wave = tid >> 6;
    const int lane = tid & 63;
    const int col  = lane & 15;
    const int quad = lane >> 4;
    const int wm   = (wave >> 1) * 64;
    const int wn   = (wave & 1) * 64;
    const long m0  = (long)blockIdx.y * 128;
    const long n0  = (long)blockIdx.x * 128;

    f32x4 zero = {0.f, 0.f, 0.f, 0.f};
    f32x4 acc[4][4];
#pragma unroll
    for (int i = 0; i < 4; i++)
#pragma unroll
        for (int j = 0; j < 4; j++) acc[i][j] = zero;

    const int srow = tid >> 2;
    const int sch  = (tid & 3) * 8;

    for (int kt = 0; kt < K; kt += 32) {
        bf16x8 av0 = cvt8(A + (m0 + srow)      * (long)K + kt + sch);
        bf16x8 av1 = cvt8(A + (m0 + srow + 64) * (long)K + kt + sch);
        bf16x8 bv0 = cvt8(Bm + (n0 + srow)      * (long)K + kt + sch);
        bf16x8 bv1 = cvt8(Bm + (n0 + srow + 64) * (long)K + kt + sch);
        *reinterpret_cast<bf16x8*>(&As[srow * 40 + sch])        = av0;
        *reinterpret_cast<bf16x8*>(&As[(srow + 64) * 40 + sch]) = av1;
        *reinterpret_cast<bf16x8*>(&Bs[srow * 40 + sch])        = bv0;
        *reinterpret_cast<bf16x8*>(&Bs[(srow + 64) * 40 + sch]) = bv1;
        __syncthreads();

        bf16x8 af[4], bfv[4];
#pragma unroll
        for (int mt = 0; mt < 4; mt++)
            af[mt] = *reinterpret_cast<const bf16x8*>(&As[(wm + mt * 16 + col) * 40 + quad * 8]);
#pragma unroll
        for (int nt = 0; nt < 4; nt++)
            bfv[nt] = *reinterpret_cast<const bf16x8*>(&Bs[(wn + nt * 16 + col) * 40 + quad * 8]);
#pragma unroll
        for (int mt = 0; mt < 4; mt++)
#pragma unroll
            for (int nt = 0; nt < 4; nt++)
                acc[mt][nt] = __builtin_amdgcn_mfma_f32_16x16x32_bf16(
                    af[mt], bfv[nt], acc[mt][nt], 0, 0, 0);
        __syncthreads();
    }

#pragma unroll
    for (int mt = 0; mt < 4; mt++) {
#pragma unroll
        for (int nt = 0; nt < 4; nt++) {
            long row = m0 + wm + mt * 16 + quad * 4;
            long cc  = n0 + wn + nt * 16 + col;
#pragma unroll
            for (int r = 0; r < 4; r++)
                store1(&C[(row + r) * (long)ldc + cc], acc[mt][nt][r]);
        }
    }
}

// ---------------------------------------------------------------------------
// RoPE on merged-KV K-part (fallback path only; fast path fuses into GEMM).
// ---------------------------------------------------------------------------
__global__ __launch_bounds__(256) void rope_kv_kernel(
    bf16* __restrict__ kvb,
    const float* __restrict__ cosb, const float* __restrict__ sinb) {
    int idx = blockIdx.x * 256 + threadIdx.x;   // B_*S_*KVH_*64 total
    int pair = idx & 63;
    int rest = idx >> 6;
    int hh   = rest % KVH_;
    int tok  = rest / KVH_;
    int s    = tok & (S_ - 1);
    long base = (long)tok * KVSTR + hh * HD_ + pair * 2;
    float c  = cosb[s * 64 + pair];
    float sn = sinb[s * 64 + pair];
    float t0 = __bfloat162float(kvb[base]);
    float t1 = __bfloat162float(kvb[base + 1]);
    kvb[base]     = __float2bfloat16(t0 * c - t1 * sn);
    kvb[base + 1] = __float2bfloat16(t0 * sn + t1 * c);
}

// ---------------------------------------------------------------------------
// Transpose V out of merged KV: kv[b*S + s][2048] (V at cols 1024+) ->
// vt[b*1024 + d][S]
// ---------------------------------------------------------------------------
__global__ __launch_bounds__(256) void transpose_v(const bf16* __restrict__ kv,
                                                   bf16* __restrict__ vt) {
    __shared__ __bf16 tile[64][72];
    const int s0 = blockIdx.x * 64;
    const int d0 = blockIdx.y * 64;
    const int b  = blockIdx.z;
    const int tid = threadIdx.x;
    const int tr  = tid >> 3;
    const int c8  = (tid & 7) * 8;
#pragma unroll
    for (int p = 0; p < 2; p++) {
        int srow = tr + p * 32;
        bf16x8 val = load8(kv + ((long)(b * S_ + s0 + srow)) * KVSTR + 1024 + d0 + c8);
        *reinterpret_cast<bf16x8*>(&tile[srow][c8]) = val;
    }
    __syncthreads();
#pragma unroll
    for (int p = 0; p < 2; p++) {
        int dd = tr + p * 32;
        bf16x8 ov;
#pragma unroll
        for (int j = 0; j < 8; j++) ov[j] = tile[c8 + j][dd];
        *reinterpret_cast<bf16x8*>(vt + ((long)(b * 1024 + d0 + dd)) * S_ + s0 + c8) = ov;
    }
}

// ---------------------------------------------------------------------------
// Windowed flash attention v8 (verified rounds 10/12): GQA head-pairing,
// depth-1 T14 reg prefetch, fused Q-RoPE at fragment load. Merged-KV reads.
// grid (S/64, H/2, B), 512 thr.
// ---------------------------------------------------------------------------
__global__ __launch_bounds__(512, 4) void attn_kernel(
    const bf16* __restrict__ q, const bf16* __restrict__ kv,
    const bf16* __restrict__ vt, bf16* __restrict__ o,
    const float* __restrict__ cosb, const float* __restrict__ sinb) {
    const int qb  = blockIdx.x;
    const int hp  = blockIdx.y;          // head pair 0..15
    const int b   = blockIdx.z;
    const int tid = threadIdx.x;
    const int wave = tid >> 6;           // 0..7
    const int lane = tid & 63;
    const int col  = lane & 15;
    const int quad = lane >> 4;
    const int h    = hp * 2 + (wave >> 2);   // this wave's head
    const int wq4  = wave & 3;               // q-row group within head
    const int kvh  = hp >> 1;                // == h>>2 (pair shares kv-head)
    const int i0   = qb * 64;
    const float scale = 0.08838834764831845f;  // 1/sqrt(128)

    __shared__ __bf16 Ks[64 * 128];   // 16 KB: slot(r, cl16) = glob chunk cl^(r&15)
    __shared__ __bf16 Vs[128 * 64];   // 16 KB: slot(d, cl8)  = glob chunk cl^(d&7)
    __shared__ __bf16 Pl[8][16 * 72]; // per-wave P tile (padded, plain ds)

    // Q A-fragments in regs with fused RoPE (verified round 10).
    const int srow = i0 + wq4 * 16 + col;    // sequence position of this lane's row
    bf16x8 qa[4];
    {
        const bf16* qptr = q + ((long)(b * S_ + srow)) * (H_ * HD_) + h * HD_ + quad * 8;
#pragma unroll
        for (int ks = 0; ks < 4; ks++) {
            bf16x8 v = load8(qptr + ks * 32);
            float4 c4 = *reinterpret_cast<const float4*>(
                cosb + (long)srow * 64 + quad * 4 + ks * 16);
            float4 s4 = *reinterpret_cast<const float4*>(
                sinb + (long)srow * 64 + quad * 4 + ks * 16);
            bf16x8 r;
            float t0, t1;
            t0 = (float)v[0]; t1 = (float)v[1];
            r[0] = (__bf16)(t0 * c4.x - t1 * s4.x); r[1] = (__bf16)(t0 * s4.x + t1 * c4.x);
            t0 = (float)v[2]; t1 = (float)v[3];
            r[2] = (__bf16)(t0 * c4.y - t1 * s4.y); r[3] = (__bf16)(t0 * s4.y + t1 * c4.y);
            t0 = (float)v[4]; t1 = (float)v[5];
            r[4] = (__bf16)(t0 * c4.z - t1 * s4.z); r[5] = (__bf16)(t0 * s4.z + t1 * c4.z);
            t0 = (float)v[6]; t1 = (float)v[7];
            r[6] = (__bf16)(t0 * c4.w - t1 * s4.w); r[7] = (__bf16)(t0 * s4.w + t1 * c4.w);
            qa[ks] = r;
        }
    }

    // staging: 8 waves x 2 loads each for K and V (1KB chunks, wave*2+i)
    long gK[2], gV[2];
    int  lK[2], lV[2];
#pragma unroll
    for (int i = 0; i < 2; i++) {
        int ck  = wave * 2 + i;                             // 0..15
        int rK  = ck * 4 + (lane >> 4);                     // 0..63
        int cgK = (lane & 15) ^ (rK & 15);
        gK[i] = ((long)(b * S_) + rK) * KVSTR + kvh * HD_ + cgK * 8;
        lK[i] = ck * 1024;
        int rV  = ck * 8 + (lane >> 3);                     // 0..127
        int cgV = (lane & 7) ^ (rV & 7);
        gV[i] = ((long)(b * 1024) + kvh * HD_ + rV) * (long)S_ + cgV * 8;
        lV[i] = ck * 1024;
    }

    f32x4 zero = {0.f, 0.f, 0.f, 0.f};
    f32x4 oacc[8];
#pragma unroll
    for (int i = 0; i < 8; i++) oacc[i] = zero;
    float lsum[4] = {0.f, 0.f, 0.f, 0.f};

    const int kb0 = (qb >= 16) ? (qb - 16) : 0;

    // prologue: load tile kb0 into registers (16B/lane x 4)
    bf16x8 kreg[2], vreg[2];
#pragma unroll
    for (int i = 0; i < 2; i++) {
        kreg[i] = *reinterpret_cast<const bf16x8*>(kv + gK[i] + (long)kb0 * 64 * KVSTR);
        vreg[i] = *reinterpret_cast<const bf16x8*>(vt + gV[i] + kb0 * 64);
    }

    for (int kb = kb0; kb <= qb; kb++) {
        GBAR();              // (A) all waves done reading the previous tile
        SCB0();
        // write tile kb (registers -> LDS, same layout gload_lds produced)
#pragma unroll
        for (int i = 0; i < 2; i++) {
            *reinterpret_cast<bf16x8*>((char*)Ks + lK[i] + lane * 16) = kreg[i];
            *reinterpret_cast<bf16x8*>((char*)Vs + lV[i] + lane * 16) = vreg[i];
        }
        LGKM0();             // my ds_writes retired
        GBAR();              // (B) all waves' tile-kb data visible
        SCB0();
        // T14: issue next tile's loads NOW — latency hides under compute(kb)
        if (kb < qb) {
#pragma unroll
            for (int i = 0; i < 2; i++) {
                kreg[i] = *reinterpret_cast<const bf16x8*>(
                    kv + gK[i] + (long)(kb + 1) * 64 * KVSTR);
                vreg[i] = *reinterpret_cast<const bf16x8*>(
                    vt + gV[i] + (kb + 1) * 64);
            }
            SCB0();          // pin the issue point before the compute body
        }

        // S = Q K^T
        f32x4 sfr[4];
        __builtin_amdgcn_s_setprio(1);
#pragma unroll
        for (int nt = 0; nt < 4; nt++) {
            f32x4 s = zero;
            int row = nt * 16 + col;
#pragma unroll
            for (int ks = 0; ks < 4; ks++) {
                bf16x8 bfv = *reinterpret_cast<const bf16x8*>(
                    (const char*)Ks + row * 256 + (((ks << 2) + quad) ^ col) * 16);
                s = __builtin_amdgcn_mfma_f32_16x16x32_bf16(qa[ks], bfv, s, 0, 0, 0);
            }
            sfr[nt] = s;
        }
        __builtin_amdgcn_s_setprio(0);
        // mask + exp + P -> per-wave LDS
#pragma unroll
        for (int nt = 0; nt < 4; nt++) {
            int j = kb * 64 + nt * 16 + col;
#pragma unroll
            for (int r = 0; r < 4; r++) {
                int i = i0 + wq4 * 16 + quad * 4 + r;
                float p = 0.f;
                if (j <= i && (i - j) < WIN_) p = __expf(sfr[nt][r] * scale);
                lsum[r] += p;
                Pl[wave][(quad * 4 + r) * 72 + nt * 16 + col] = __float2bfloat16(p);
            }
        }
        // O += P V
        __builtin_amdgcn_s_setprio(1);
#pragma unroll
        for (int ks2 = 0; ks2 < 2; ks2++) {
            bf16x8 pa = *reinterpret_cast<const bf16x8*>(
                &Pl[wave][col * 72 + ks2 * 32 + quad * 8]);
#pragma unroll
            for (int nt2 = 0; nt2 < 8; nt2++) {
                int d = nt2 * 16 + col;
                bf16x8 vb = *reinterpret_cast<const bf16x8*>(
                    (const char*)Vs + d * 128 + ((((ks2 << 2) + quad)) ^ (col & 7)) * 16);
                oacc[nt2] = __builtin_amdgcn_mfma_f32_16x16x32_bf16(
                    pa, vb, oacc[nt2], 0, 0, 0);
            }
        }
        __builtin_amdgcn_s_setprio(0);
    }

    // lsum across the 16 col-lanes of each quad group
#pragma unroll
    for (int m = 1; m < 16; m <<= 1) {
#pragma unroll
        for (int r = 0; r < 4; r++) lsum[r] += __shfl_xor(lsum[r], m, 64);
    }

    bf16* op = o + ((long)(b * S_ + i0 + wq4 * 16 + quad * 4)) * (H_ * HD_) + h * HD_;
#pragma unroll
    for (int nt2 = 0; nt2 < 8; nt2++) {
#pragma unroll
        for (int r = 0; r < 4; r++)
            op[(long)r * (H_ * HD_) + nt2 * 16 + col] =
                __float2bfloat16(oacc[nt2][r] / lsum[r]);
    }
}

// ---------------------------------------------------------------------------
extern "C" void kernel_launch(void* const* d_in, const int* in_sizes, int n_in,
                              void* d_out, int out_size, void* d_ws, size_t ws_size,
                              hipStream_t stream) {
    const float* x    = (const float*)d_in[0];
    const float* wq   = (const float*)d_in[1];
    const float* wk   = (const float*)d_in[2];
    const float* wv   = (const float*)d_in[3];
    const float* wo   = (const float*)d_in[4];
    const float* cosb = (const float*)d_in[5];
    const float* sinb = (const float*)d_in[6];
    float* out = (float*)d_out;

    const size_t T   = (size_t)B_ * S_;        // 4096 tokens
    const size_t SZ_D  = T * (H_ * HD_);       // 16.78M elements
    const size_t SZ_KV = T * (KVH_ * HD_);     // 4.19M elements

    dim3 blk(256);
    // fast path needs: xb + wbuf + q + kv + vt + ao
    const size_t need_fast = (SZ_D * 3 + SZ_KV * 3 + SZ_D) * 2;  // bytes

    if (ws_size >= need_fast) {
        bf16* xb    = (bf16*)d_ws;          // x cast          (SZ_D)
        bf16* wbuf  = xb    + SZ_D;         // weight cast     (SZ_D, reused serially)
        bf16* q_ws  = wbuf  + SZ_D;         // Q               (SZ_D)
        bf16* kv_ws = q_ws  + SZ_D;         // merged K|V      (2*SZ_KV)
        bf16* vt_ws = kv_ws + 2 * SZ_KV;    // V^T             (SZ_KV)
        bf16* ao_ws = vt_ws + SZ_KV;        // attn out        (SZ_D)

        // cast x and wq together, then Q-proj
        cast2_kernel<<<2 * (SZ_D / 2048), blk, 0, stream>>>(x, xb, wq, wbuf,
                                                            (int)(SZ_D / 2048));
        gemm_nt_256<bf16><<<dim3(16, 16), dim3(512), 0, stream>>>(xb, wbuf, q_ws, 4096, 4096, 4096);

        // cast wk+wv stacked, merged KV-proj with FUSED K-RoPE epilogue
        cast2_kernel<<<2 * (SZ_KV / 2048), blk, 0, stream>>>(wk, wbuf, wv, wbuf + SZ_KV,
                                                             (int)(SZ_KV / 2048));
        gemm_nt_fast_rope<<<dim3(16, 32), blk, 0, stream>>>(
            xb, wbuf, kv_ws, 4096, 2048, 4096, cosb, sinb);

        // V-transpose only (K already roped; Q-rope fused into attn)
        transpose_v<<<dim3(32, 16, 2), blk, 0, stream>>>(kv_ws, vt_ws);

        attn_kernel<<<dim3(32, 16, 2), dim3(512), 0, stream>>>(
            q_ws, kv_ws, vt_ws, ao_ws, cosb, sinb);

        cast_kernel<<<SZ_D / 2048, blk, 0, stream>>>(wo, wbuf);
        gemm_nt_256<float><<<dim3(16, 16), dim3(512), 0, stream>>>(ao_ws, wbuf, out, 4096, 4096, 4096);
    } else {
        // fallback: slow GEMMs straight from f32 inputs (fits in ~92 MB ws)
        bf16* q_ws  = (bf16*)d_ws;
        bf16* kv_ws = q_ws  + SZ_D;
        bf16* vt_ws = kv_ws + 2 * SZ_KV;
        bf16* ao_ws = vt_ws + SZ_KV;

        gemm_nt<float, float, bf16><<<dim3(32, 32), blk, 0, stream>>>(x, wq, q_ws, 4096, 4096, 4096, 4096);
        gemm_nt<float, float, bf16><<<dim3(8, 32),  blk, 0, stream>>>(x, wk, kv_ws, 4096, 1024, 4096, KVSTR);
        gemm_nt<float, float, bf16><<<dim3(8, 32),  blk, 0, stream>>>(x, wv, kv_ws + 1024, 4096, 1024, 4096, KVSTR);

        rope_kv_kernel<<<(B_ * S_ * KVH_ * 64) / 256, blk, 0, stream>>>(
            kv_ws, cosb, sinb);
        transpose_v<<<dim3(32, 16, 2), blk, 0, stream>>>(kv_ws, vt_ws);

        attn_kernel<<<dim3(32, 16, 2), dim3(512), 0, stream>>>(
            q_ws, kv_ws, vt_ws, ao_ws, cosb, sinb);

        gemm_nt<bf16, float, float><<<dim3(32, 32), blk, 0, stream>>>(ao_ws, wo, out, 4096, 4096, 4096, 4096);
    }
}

// Round 14
// 666.870 us; speedup vs baseline: 1.0030x; 1.0030x over previous
//
#include <hip/hip_runtime.h>
#include <hip/hip_bf16.h>

// Problem constants
#define B_  2
#define S_  2048
#define D_  4096
#define H_  32
#define KVH_ 8
#define HD_ 128
#define WIN_ 1024
#define KVSTR 2048   // merged KV row stride (K cols 0-1023, V cols 1024-2047)

typedef __attribute__((ext_vector_type(8))) __bf16 bf16x8;
typedef __attribute__((ext_vector_type(4))) float f32x4;
using bf16 = __hip_bfloat16;

typedef const __attribute__((address_space(1))) void* gas_ptr;
typedef __attribute__((address_space(3))) void* las_ptr;

// async global->LDS, 16B per lane; lds dest = (wave-uniform) l + lane*16
__device__ __forceinline__ void gload16(const void* g, void* l) {
    __builtin_amdgcn_global_load_lds((gas_ptr)g, (las_ptr)l, 16, 0, 0);
}

__device__ __forceinline__ bf16x8 load8(const bf16* p) {
    return *reinterpret_cast<const bf16x8*>(p);
}
__device__ __forceinline__ bf16x8 cvt8(const bf16* p) {
    return *reinterpret_cast<const bf16x8*>(p);
}
__device__ __forceinline__ bf16x8 cvt8(const float* p) {
    const float4* q = reinterpret_cast<const float4*>(p);
    float4 a = q[0], b = q[1];
    bf16x8 r;
    r[0] = (__bf16)a.x; r[1] = (__bf16)a.y; r[2] = (__bf16)a.z; r[3] = (__bf16)a.w;
    r[4] = (__bf16)b.x; r[5] = (__bf16)b.y; r[6] = (__bf16)b.z; r[7] = (__bf16)b.w;
    return r;
}
__device__ __forceinline__ void store1(float* p, float v) { *p = v; }
__device__ __forceinline__ void store1(bf16* p, float v) { *p = __float2bfloat16(v); }

#define GBAR()  __builtin_amdgcn_s_barrier()
#define SCB0()  __builtin_amdgcn_sched_barrier(0)
#define LGKM0() do { asm volatile("s_waitcnt lgkmcnt(0)" ::: "memory"); \
                     __builtin_amdgcn_sched_barrier(0); } while (0)
#define VMC(n)  do { asm volatile("s_waitcnt vmcnt(" #n ")" ::: "memory"); \
                     __builtin_amdgcn_sched_barrier(0); } while (0)

// ---------------------------------------------------------------------------
// f32 -> bf16 cast, 8 elements/thread, exact-size launch (n % 2048 == 0)
// ---------------------------------------------------------------------------
__global__ __launch_bounds__(256) void cast_kernel(const float* __restrict__ in,
                                                   bf16* __restrict__ out) {
    long i = ((long)blockIdx.x * 256 + threadIdx.x) * 8;
    const float4* p = reinterpret_cast<const float4*>(in + i);
    float4 a = p[0], b = p[1];
    bf16x8 r;
    r[0] = (__bf16)a.x; r[1] = (__bf16)a.y; r[2] = (__bf16)a.z; r[3] = (__bf16)a.w;
    r[4] = (__bf16)b.x; r[5] = (__bf16)b.y; r[6] = (__bf16)b.z; r[7] = (__bf16)b.w;
    *reinterpret_cast<bf16x8*>(out + i) = r;
}

// two casts in one launch: blocks [0,n0) -> pair0, rest -> pair1
__global__ __launch_bounds__(256) void cast2_kernel(
    const float* __restrict__ in0, bf16* __restrict__ out0,
    const float* __restrict__ in1, bf16* __restrict__ out1, int n0blocks) {
    const bool first = (int)blockIdx.x < n0blocks;
    const float* in = first ? in0 : in1;
    bf16* out = first ? out0 : out1;
    long bid = first ? blockIdx.x : (blockIdx.x - n0blocks);
    long i = (bid * 256 + threadIdx.x) * 8;
    const float4* p = reinterpret_cast<const float4*>(in + i);
    float4 a = p[0], b = p[1];
    bf16x8 r;
    r[0] = (__bf16)a.x; r[1] = (__bf16)a.y; r[2] = (__bf16)a.z; r[3] = (__bf16)a.w;
    r[4] = (__bf16)b.x; r[5] = (__bf16)b.y; r[6] = (__bf16)b.z; r[7] = (__bf16)b.w;
    *reinterpret_cast<bf16x8*>(out + i) = r;
}

// T1 XCD swizzle: requires nwg % 8 == 0 (all our grids: 256, 512).
__device__ __forceinline__ void xcd_swizzle(int& bx, int& by, int nbx, int nby) {
    int flat = bx + nbx * by;
    int nwg  = nbx * nby;
    int cpx  = nwg >> 3;
    int swz  = (flat & 7) * cpx + (flat >> 3);
    bx = swz % nbx;
    by = swz / nbx;
}

// ---------------------------------------------------------------------------
// 256x256 deep-pipelined NT GEMM (bf16 in): C = A[M,K] @ B[N,K]^T.
// 8 waves (2Mx4N), BK=64, 2-deep LDS dbuf (128 KiB), 4 phases/K-tile.
// Counted vmcnt(6). NOTE: 128 KiB LDS -> 1 block/CU; grid must be <=256
// (round-11 lesson). [verified rounds 2/5/6/7/8/10/12]
// ---------------------------------------------------------------------------
template <typename TC>
__global__ __launch_bounds__(512, 2) void gemm_nt_256(
    const bf16* __restrict__ A, const bf16* __restrict__ Bm,
    TC* __restrict__ C, int M, int N, int K) {
    // [buf][0=A,1=B][256 rows x 64 cols]
    __shared__ __bf16 lds[2][2][256 * 64];   // 128 KiB

    const int tid  = threadIdx.x;
    const int wave = tid >> 6;          // 0..7
    const int lane = tid & 63;
    const int col  = lane & 15;
    const int quad = lane >> 4;
    const int c7   = col & 7;
    const int wmi  = wave >> 2;         // 0..1  (M half)
    const int wni  = wave & 3;          // 0..3  (N quarter)
    int bx = blockIdx.x, by = blockIdx.y;
    xcd_swizzle(bx, by, gridDim.x, gridDim.y);
    const long m0  = (long)by * 256;
    const long n0  = (long)bx * 256;
    const int  nt  = K >> 6;            // K-tiles

    f32x4 zero = {0.f, 0.f, 0.f, 0.f};
    f32x4 acc[8][4];
#pragma unroll
    for (int i = 0; i < 8; i++)
#pragma unroll
        for (int j = 0; j < 4; j++) acc[i][j] = zero;

    // staging: load j covers rows j*64 + wave*8 .. +7 (this wave's slice)
    long gA[4], gB[4];
    int  lofs[4];
#pragma unroll
    for (int j = 0; j < 4; j++) {
        int r  = j * 64 + wave * 8 + (lane >> 3);
        int cg = (lane & 7) ^ (r & 7);          // pre-swizzled source chunk
        gA[j]   = (m0 + r) * (long)K + cg * 8;
        gB[j]   = (n0 + r) * (long)K + cg * 8;
        lofs[j] = (j * 64 + wave * 8) * 128;    // bytes; HW adds lane*16
    }

    // ---- prologue: tile0 full (8) + tile1 B(4)+A-lo(2) = 14 loads ----
#pragma unroll
    for (int j = 0; j < 4; j++) {
        gload16(A  + gA[j], (char*)lds[0][0] + lofs[j]);
        gload16(Bm + gB[j], (char*)lds[0][1] + lofs[j]);
    }
    if (nt > 1) {
#pragma unroll
        for (int j = 0; j < 4; j++)
            gload16(Bm + gB[j] + 64, (char*)lds[1][1] + lofs[j]);
        gload16(A + gA[0] + 64, (char*)lds[1][0] + lofs[0]);
        gload16(A + gA[2] + 64, (char*)lds[1][0] + lofs[2]);
        VMC(6);
    } else {
        VMC(0);
    }
    GBAR();

#define RDA_(dst, mf, ks) \
    dst = *reinterpret_cast<const bf16x8*>(Ab + (wmi * 128 + (mf) * 16 + col) * 128 \
                                              + ((((ks) << 2) + quad) ^ c7) * 16)
#define MFMA16(mb) \
    do { \
        _Pragma("unroll") \
        for (int ks = 0; ks < 2; ks++) { \
            _Pragma("unroll") \
            for (int nf = 0; nf < 4; nf++) { \
                acc[mb][nf]     = __builtin_amdgcn_mfma_f32_16x16x32_bf16( \
                    a[0][ks], bfr[nf][ks], acc[mb][nf], 0, 0, 0); \
                acc[mb + 1][nf] = __builtin_amdgcn_mfma_f32_16x16x32_bf16( \
                    a[1][ks], bfr[nf][ks], acc[mb + 1][nf], 0, 0, 0); \
            } \
        } \
    } while (0)

    for (int t = 0; t < nt; ++t) {
        const int cur = t & 1;
        const char* Ab = (const char*)lds[cur][0];
        const char* Bb = (const char*)lds[cur][1];
        char* An2 = (char*)lds[cur ^ 1][0];   // tile t+1 A (finish hi rows)
        char* Ac2 = (char*)lds[cur][0];       // tile t+2 A (parity == t)
        char* Bc2 = (char*)lds[cur][1];       // tile t+2 B

        // ---------------- P1 ----------------
        bf16x8 bfr[4][2];
#pragma unroll
        for (int nf = 0; nf < 4; nf++)
#pragma unroll
            for (int ks = 0; ks < 2; ks++)
                bfr[nf][ks] = *reinterpret_cast<const bf16x8*>(
                    Bb + (wni * 64 + nf * 16 + col) * 128 + (((ks << 2) + quad) ^ c7) * 16);
        bf16x8 a[2][2];
        RDA_(a[0][0], 0, 0); RDA_(a[0][1], 0, 1);
        RDA_(a[1][0], 1, 0); RDA_(a[1][1], 1, 1);
        if (t + 1 < nt) {                      // stage A hi-rows of tile t+1
            long ko = (long)(t + 1) * 64;
            gload16(A + gA[1] + ko, An2 + lofs[1]);
            gload16(A + gA[3] + ko, An2 + lofs[3]);
        }
        GBAR();
        LGKM0();
        __builtin_amdgcn_s_setprio(1);
        MFMA16(0);
        __builtin_amdgcn_s_setprio(0);
        GBAR();

        // ---------------- P2 ----------------
        RDA_(a[0][0], 2, 0); RDA_(a[0][1], 2, 1);
        RDA_(a[1][0], 3, 0); RDA_(a[1][1], 3, 1);
        if (t + 2 < nt) {                      // stage B of tile t+2
            long ko = (long)(t + 2) * 64;
#pragma unroll
            for (int j = 0; j < 4; j++)
                gload16(Bm + gB[j] + ko, Bc2 + lofs[j]);
        }
        GBAR();
        LGKM0();
        __builtin_amdgcn_s_setprio(1);
        MFMA16(2);
        __builtin_amdgcn_s_setprio(0);
        GBAR();

        // ---------------- P3 ----------------
        RDA_(a[0][0], 4, 0); RDA_(a[0][1], 4, 1);
        RDA_(a[1][0], 5, 0); RDA_(a[1][1], 5, 1);
        if (t + 2 < nt) {                      // stage A lo-rows of tile t+2
            long ko = (long)(t + 2) * 64;
            gload16(A + gA[0] + ko, Ac2 + lofs[0]);
            gload16(A + gA[2] + ko, Ac2 + lofs[2]);
        }
        GBAR();
        LGKM0();
        __builtin_amdgcn_s_setprio(1);
        MFMA16(4);
        __builtin_amdgcn_s_setprio(0);
        GBAR();

        // ---------------- P4 ----------------
        RDA_(a[0][0], 6, 0); RDA_(a[0][1], 6, 1);
        RDA_(a[1][0], 7, 0); RDA_(a[1][1], 7, 1);
        LGKM0();
        __builtin_amdgcn_s_setprio(1);
        MFMA16(6);
        __builtin_amdgcn_s_setprio(0);
        if (t + 2 < nt) { VMC(6); } else { VMC(0); }
        GBAR();
    }

    // C/D layout: col=lane&15, row=quad*4+reg  [m89/m91 verified]
#pragma unroll
    for (int mf = 0; mf < 8; mf++) {
#pragma unroll
        for (int nf = 0; nf < 4; nf++) {
            long row = m0 + wmi * 128 + mf * 16 + quad * 4;
            long cc  = n0 + wni * 64 + nf * 16 + col;
#pragma unroll
            for (int r = 0; r < 4; r++)
                store1(&C[(row + r) * (long)N + cc], acc[mf][nf][r]);
        }
    }
}

// ---------------------------------------------------------------------------
// FAST NT GEMM (bf16 in): C[M,N] = A[M,K] @ B[N,K]^T, f32 accumulate.
// 128x128 tile, BK=64 — used for the MERGED K+V projection (N=2048).
// ---------------------------------------------------------------------------
template <typename TC>
__global__ __launch_bounds__(256) void gemm_nt_fast(
    const bf16* __restrict__ A, const bf16* __restrict__ Bm,
    TC* __restrict__ C, int M, int N, int K) {
    __shared__ __bf16 As[128 * 64];   // 16 KB, swizzled, unpadded
    __shared__ __bf16 Bs[128 * 64];

    const int tid  = threadIdx.x;
    const int wave = tid >> 6;
    const int lane = tid & 63;
    const int col  = lane & 15;
    const int quad = lane >> 4;
    const int c7   = col & 7;
    const int wm   = (wave >> 1) * 64;
    const int wn   = (wave & 1) * 64;
    int bx = blockIdx.x, by = blockIdx.y;
    xcd_swizzle(bx, by, gridDim.x, gridDim.y);
    const long m0  = (long)by * 128;
    const long n0  = (long)bx * 128;

    f32x4 zero = {0.f, 0.f, 0.f, 0.f};
    f32x4 acc[4][4];
#pragma unroll
    for (int i = 0; i < 4; i++)
#pragma unroll
        for (int j = 0; j < 4; j++) acc[i][j] = zero;

    long goffA[4], goffB[4];
    int  loff[4];
#pragma unroll
    for (int i = 0; i < 4; i++) {
        int r  = (wave * 4 + i) * 8 + (lane >> 3);
        int cg = (lane & 7) ^ (r & 7);
        goffA[i] = (m0 + r) * (long)K + cg * 8;
        goffB[i] = (n0 + r) * (long)K + cg * 8;
        loff[i]  = (wave * 4 + i) * 1024;   // bytes; HW adds lane*16
    }

    for (int kt = 0; kt < K; kt += 64) {
#pragma unroll
        for (int i = 0; i < 4; i++) {
            gload16(A + goffA[i] + kt, (char*)As + loff[i]);
            gload16(Bm + goffB[i] + kt, (char*)Bs + loff[i]);
        }
        __syncthreads();

        bf16x8 af[2][4], bfv[2][4];
#pragma unroll
        for (int ks = 0; ks < 2; ks++) {
#pragma unroll
            for (int mt = 0; mt < 4; mt++) {
                int row = wm + mt * 16 + col;
                af[ks][mt] = *reinterpret_cast<const bf16x8*>(
                    (const char*)As + row * 128 + (((ks << 2) + quad) ^ c7) * 16);
            }
#pragma unroll
            for (int nt = 0; nt < 4; nt++) {
                int row = wn + nt * 16 + col;
                bfv[ks][nt] = *reinterpret_cast<const bf16x8*>(
                    (const char*)Bs + row * 128 + (((ks << 2) + quad) ^ c7) * 16);
            }
        }
#pragma unroll
        for (int ks = 0; ks < 2; ks++)
#pragma unroll
            for (int mt = 0; mt < 4; mt++)
#pragma unroll
                for (int nt = 0; nt < 4; nt++)
                    acc[mt][nt] = __builtin_amdgcn_mfma_f32_16x16x32_bf16(
                        af[ks][mt], bfv[ks][nt], acc[mt][nt], 0, 0, 0);
        __syncthreads();
    }

#pragma unroll
    for (int mt = 0; mt < 4; mt++) {
#pragma unroll
        for (int nt = 0; nt < 4; nt++) {
            long row = m0 + wm + mt * 16 + quad * 4;
            long cc  = n0 + wn + nt * 16 + col;
#pragma unroll
            for (int r = 0; r < 4; r++)
                store1(&C[(row + r) * (long)N + cc], acc[mt][nt][r]);
        }
    }
}

// ---------------------------------------------------------------------------
// SLOW NT GEMM (f32/bf16 in, convert at staging) — fallback if ws too small.
// ---------------------------------------------------------------------------
template <typename TA, typename TB, typename TC>
__global__ __launch_bounds__(256) void gemm_nt(
    const TA* __restrict__ A, const TB* __restrict__ Bm,
    TC* __restrict__ C, int M, int N, int K, int ldc) {
    __shared__ __bf16 As[128 * 40];
    __shared__ __bf16 Bs[128 * 40];

    const int tid  = threadIdx.x;
    const int wave = tid >> 6;
    const int lane = tid & 63;
    const int col  = lane & 15;
    const int quad = lane >> 4;
    const int wm   = (wave >> 1) * 64;
    const int wn   = (wave & 1) * 64;
    const long m0  = (long)blockIdx.y * 128;
    const long n0  = (long)blockIdx.x * 128;

    f32x4 zero = {0.f, 0.f, 0.f, 0.f};
    f32x4 acc[4][4];
#pragma unroll
    for (int i = 0; i < 4; i++)
#pragma unroll
        for (int j = 0; j < 4; j++) acc[i][j] = zero;

    const int srow = tid >> 2;
    const int sch  = (tid & 3) * 8;

    for (int kt = 0; kt < K; kt += 32) {
        bf16x8 av0 = cvt8(A + (m0 + srow)      * (long)K + kt + sch);
        bf16x8 av1 = cvt8(A + (m0 + srow + 64) * (long)K + kt + sch);
        bf16x8 bv0 = cvt8(Bm + (n0 + srow)      * (long)K + kt + sch);
        bf16x8 bv1 = cvt8(Bm + (n0 + srow + 64) * (long)K + kt + sch);
        *reinterpret_cast<bf16x8*>(&As[srow * 40 + sch])        = av0;
        *reinterpret_cast<bf16x8*>(&As[(srow + 64) * 40 + sch]) = av1;
        *reinterpret_cast<bf16x8*>(&Bs[srow * 40 + sch])        = bv0;
        *reinterpret_cast<bf16x8*>(&Bs[(srow + 64) * 40 + sch]) = bv1;
        __syncthreads();

        bf16x8 af[4], bfv[4];
#pragma unroll
        for (int mt = 0; mt < 4; mt++)
            af[mt] = *reinterpret_cast<const bf16x8*>(&As[(wm + mt * 16 + col) * 40 + quad * 8]);
#pragma unroll
        for (int nt = 0; nt < 4; nt++)
            bfv[nt] = *reinterpret_cast<const bf16x8*>(&Bs[(wn + nt * 16 + col) * 40 + quad * 8]);
#pragma unroll
        for (int mt = 0; mt < 4; mt++)
#pragma unroll
            for (int nt = 0; nt < 4; nt++)
                acc[mt][nt] = __builtin_amdgcn_mfma_f32_16x16x32_bf16(
                    af[mt], bfv[nt], acc[mt][nt], 0, 0, 0);
        __syncthreads();
    }

#pragma unroll
    for (int mt = 0; mt < 4; mt++) {
#pragma unroll
        for (int nt = 0; nt < 4; nt++) {
            long row = m0 + wm + mt * 16 + quad * 4;
            long cc  = n0 + wn + nt * 16 + col;
#pragma unroll
            for (int r = 0; r < 4; r++)
                store1(&C[(row + r) * (long)ldc + cc], acc[mt][nt][r]);
        }
    }
}

// ---------------------------------------------------------------------------
// FUSED K-RoPE + V-transpose, one launch. Blocks [0, NROPE) rope the K part
// of kv (cols 0-1023); blocks [NROPE, NROPE+1024) transpose V (cols 1024+)
// into vt. Disjoint data -> no ordering hazard within the launch.
// ---------------------------------------------------------------------------
__global__ __launch_bounds__(256) void rope_tr_kernel(
    bf16* __restrict__ kv, bf16* __restrict__ vt,
    const float* __restrict__ cosb, const float* __restrict__ sinb) {
    const int NROPE = (B_ * S_ * KVH_ * 64) / 256;   // 8192 blocks
    __shared__ __bf16 tile[64][72];
    if ((int)blockIdx.x < NROPE) {
        int idx = blockIdx.x * 256 + threadIdx.x;
        int pair = idx & 63;
        int rest = idx >> 6;
        int hh   = rest % KVH_;
        int tok  = rest / KVH_;
        int s    = tok & (S_ - 1);
        long base = (long)tok * KVSTR + hh * HD_ + pair * 2;
        float c  = cosb[s * 64 + pair];
        float sn = sinb[s * 64 + pair];
        float t0 = __bfloat162float(kv[base]);
        float t1 = __bfloat162float(kv[base + 1]);
        kv[base]     = __float2bfloat16(t0 * c - t1 * sn);
        kv[base + 1] = __float2bfloat16(t0 * sn + t1 * c);
    } else {
        int bid = blockIdx.x - NROPE;        // 0..1023
        const int s0 = (bid & 31) * 64;
        const int d0 = ((bid >> 5) & 15) * 64;
        const int b  = bid >> 9;
        const int tid = threadIdx.x;
        const int tr  = tid >> 3;
        const int c8  = (tid & 7) * 8;
#pragma unroll
        for (int p = 0; p < 2; p++) {
            int srow = tr + p * 32;
            bf16x8 val = load8(kv + ((long)(b * S_ + s0 + srow)) * KVSTR + 1024 + d0 + c8);
            *reinterpret_cast<bf16x8*>(&tile[srow][c8]) = val;
        }
        __syncthreads();
#pragma unroll
        for (int p = 0; p < 2; p++) {
            int dd = tr + p * 32;
            bf16x8 ov;
#pragma unroll
            for (int j = 0; j < 8; j++) ov[j] = tile[c8 + j][dd];
            *reinterpret_cast<bf16x8*>(vt + ((long)(b * 1024 + d0 + dd)) * S_ + s0 + c8) = ov;
        }
    }
}

// ---------------------------------------------------------------------------
// Windowed flash attention v8 (verified round 10): GQA head-pairing, depth-1
// T14 reg prefetch, fused Q-RoPE at fragment load. Merged-KV reads (2048).
// grid (S/64, H/2, B), 512 thr.
// ---------------------------------------------------------------------------
__global__ __launch_bounds__(512, 4) void attn_kernel(
    const bf16* __restrict__ q, const bf16* __restrict__ kv,
    const bf16* __restrict__ vt, bf16* __restrict__ o,
    const float* __restrict__ cosb, const float* __restrict__ sinb) {
    const int qb  = blockIdx.x;
    const int hp  = blockIdx.y;          // head pair 0..15
    const int b   = blockIdx.z;
    const int tid = threadIdx.x;
    const int wave = tid >> 6;           // 0..7
    const int lane = tid & 63;
    const int col  = lane & 15;
    const int quad = lane >> 4;
    const int h    = hp * 2 + (wave >> 2);   // this wave's head
    const int wq4  = wave & 3;               // q-row group within head
    const int kvh  = hp >> 1;                // == h>>2 (pair shares kv-head)
    const int i0   = qb * 64;
    const float scale = 0.08838834764831845f;  // 1/sqrt(128)

    __shared__ __bf16 Ks[64 * 128];   // 16 KB: slot(r, cl16) = glob chunk cl^(r&15)
    __shared__ __bf16 Vs[128 * 64];   // 16 KB: slot(d, cl8)  = glob chunk cl^(d&7)
    __shared__ __bf16 Pl[8][16 * 72]; // per-wave P tile (padded, plain ds)

    // Q A-fragments in regs with fused RoPE (verified round 10).
    const int srow = i0 + wq4 * 16 + col;    // sequence position of this lane's row
    bf16x8 qa[4];
    {
        const bf16* qptr = q + ((long)(b * S_ + srow)) * (H_ * HD_) + h * HD_ + quad * 8;
#pragma unroll
        for (int ks = 0; ks < 4; ks++) {
            bf16x8 v = load8(qptr + ks * 32);
            float4 c4 = *reinterpret_cast<const float4*>(
                cosb + (long)srow * 64 + quad * 4 + ks * 16);
            float4 s4 = *reinterpret_cast<const float4*>(
                sinb + (long)srow * 64 + quad * 4 + ks * 16);
            bf16x8 r;
            float t0, t1;
            t0 = (float)v[0]; t1 = (float)v[1];
            r[0] = (__bf16)(t0 * c4.x - t1 * s4.x); r[1] = (__bf16)(t0 * s4.x + t1 * c4.x);
            t0 = (float)v[2]; t1 = (float)v[3];
            r[2] = (__bf16)(t0 * c4.y - t1 * s4.y); r[3] = (__bf16)(t0 * s4.y + t1 * c4.y);
            t0 = (float)v[4]; t1 = (float)v[5];
            r[4] = (__bf16)(t0 * c4.z - t1 * s4.z); r[5] = (__bf16)(t0 * s4.z + t1 * c4.z);
            t0 = (float)v[6]; t1 = (float)v[7];
            r[6] = (__bf16)(t0 * c4.w - t1 * s4.w); r[7] = (__bf16)(t0 * s4.w + t1 * c4.w);
            qa[ks] = r;
        }
    }

    // staging: 8 waves x 2 loads each for K and V (1KB chunks, wave*2+i)
    long gK[2], gV[2];
    int  lK[2], lV[2];
#pragma unroll
    for (int i = 0; i < 2; i++) {
        int ck  = wave * 2 + i;                             // 0..15
        int rK  = ck * 4 + (lane >> 4);                     // 0..63
        int cgK = (lane & 15) ^ (rK & 15);
        gK[i] = ((long)(b * S_) + rK) * KVSTR + kvh * HD_ + cgK * 8;
        lK[i] = ck * 1024;
        int rV  = ck * 8 + (lane >> 3);                     // 0..127
        int cgV = (lane & 7) ^ (rV & 7);
        gV[i] = ((long)(b * 1024) + kvh * HD_ + rV) * (long)S_ + cgV * 8;
        lV[i] = ck * 1024;
    }

    f32x4 zero = {0.f, 0.f, 0.f, 0.f};
    f32x4 oacc[8];
#pragma unroll
    for (int i = 0; i < 8; i++) oacc[i] = zero;
    float lsum[4] = {0.f, 0.f, 0.f, 0.f};

    const int kb0 = (qb >= 16) ? (qb - 16) : 0;

    // prologue: load tile kb0 into registers (16B/lane x 4)
    bf16x8 kreg[2], vreg[2];
#pragma unroll
    for (int i = 0; i < 2; i++) {
        kreg[i] = *reinterpret_cast<const bf16x8*>(kv + gK[i] + (long)kb0 * 64 * KVSTR);
        vreg[i] = *reinterpret_cast<const bf16x8*>(vt + gV[i] + kb0 * 64);
    }

    for (int kb = kb0; kb <= qb; kb++) {
        GBAR();              // (A) all waves done reading the previous tile
        SCB0();
        // write tile kb (registers -> LDS, same layout gload_lds produced)
#pragma unroll
        for (int i = 0; i < 2; i++) {
            *reinterpret_cast<bf16x8*>((char*)Ks + lK[i] + lane * 16) = kreg[i];
            *reinterpret_cast<bf16x8*>((char*)Vs + lV[i] + lane * 16) = vreg[i];
        }
        LGKM0();             // my ds_writes retired
        GBAR();              // (B) all waves' tile-kb data visible
        SCB0();
        // T14: issue next tile's loads NOW — latency hides under compute(kb)
        if (kb < qb) {
#pragma unroll
            for (int i = 0; i < 2; i++) {
                kreg[i] = *reinterpret_cast<const bf16x8*>(
                    kv + gK[i] + (long)(kb + 1) * 64 * KVSTR);
                vreg[i] = *reinterpret_cast<const bf16x8*>(
                    vt + gV[i] + (kb + 1) * 64);
            }
            SCB0();          // pin the issue point before the compute body
        }

        // S = Q K^T
        f32x4 sfr[4];
        __builtin_amdgcn_s_setprio(1);
#pragma unroll
        for (int nt = 0; nt < 4; nt++) {
            f32x4 s = zero;
            int row = nt * 16 + col;
#pragma unroll
            for (int ks = 0; ks < 4; ks++) {
                bf16x8 bfv = *reinterpret_cast<const bf16x8*>(
                    (const char*)Ks + row * 256 + (((ks << 2) + quad) ^ col) * 16);
                s = __builtin_amdgcn_mfma_f32_16x16x32_bf16(qa[ks], bfv, s, 0, 0, 0);
            }
            sfr[nt] = s;
        }
        __builtin_amdgcn_s_setprio(0);
        // mask + exp + P -> per-wave LDS
#pragma unroll
        for (int nt = 0; nt < 4; nt++) {
            int j = kb * 64 + nt * 16 + col;
#pragma unroll
            for (int r = 0; r < 4; r++) {
                int i = i0 + wq4 * 16 + quad * 4 + r;
                float p = 0.f;
                if (j <= i && (i - j) < WIN_) p = __expf(sfr[nt][r] * scale);
                lsum[r] += p;
                Pl[wave][(quad * 4 + r) * 72 + nt * 16 + col] = __float2bfloat16(p);
            }
        }
        // O += P V
        __builtin_amdgcn_s_setprio(1);
#pragma unroll
        for (int ks2 = 0; ks2 < 2; ks2++) {
            bf16x8 pa = *reinterpret_cast<const bf16x8*>(
                &Pl[wave][col * 72 + ks2 * 32 + quad * 8]);
#pragma unroll
            for (int nt2 = 0; nt2 < 8; nt2++) {
                int d = nt2 * 16 + col;
                bf16x8 vb = *reinterpret_cast<const bf16x8*>(
                    (const char*)Vs + d * 128 + ((((ks2 << 2) + quad)) ^ (col & 7)) * 16);
                oacc[nt2] = __builtin_amdgcn_mfma_f32_16x16x32_bf16(
                    pa, vb, oacc[nt2], 0, 0, 0);
            }
        }
        __builtin_amdgcn_s_setprio(0);
    }

    // lsum across the 16 col-lanes of each quad group
#pragma unroll
    for (int m = 1; m < 16; m <<= 1) {
#pragma unroll
        for (int r = 0; r < 4; r++) lsum[r] += __shfl_xor(lsum[r], m, 64);
    }

    bf16* op = o + ((long)(b * S_ + i0 + wq4 * 16 + quad * 4)) * (H_ * HD_) + h * HD_;
#pragma unroll
    for (int nt2 = 0; nt2 < 8; nt2++) {
#pragma unroll
        for (int r = 0; r < 4; r++)
            op[(long)r * (H_ * HD_) + nt2 * 16 + col] =
                __float2bfloat16(oacc[nt2][r] / lsum[r]);
    }
}

// ---------------------------------------------------------------------------
extern "C" void kernel_launch(void* const* d_in, const int* in_sizes, int n_in,
                              void* d_out, int out_size, void* d_ws, size_t ws_size,
                              hipStream_t stream) {
    const float* x    = (const float*)d_in[0];
    const float* wq   = (const float*)d_in[1];
    const float* wk   = (const float*)d_in[2];
    const float* wv   = (const float*)d_in[3];
    const float* wo   = (const float*)d_in[4];
    const float* cosb = (const float*)d_in[5];
    const float* sinb = (const float*)d_in[6];
    float* out = (float*)d_out;

    const size_t T   = (size_t)B_ * S_;        // 4096 tokens
    const size_t SZ_D  = T * (H_ * HD_);       // 16.78M elements
    const size_t SZ_KV = T * (KVH_ * HD_);     // 4.19M elements

    dim3 blk(256);
    // fast path needs: xb + wbuf + q + kv + vt + ao
    const size_t need_fast = (SZ_D * 3 + SZ_KV * 3 + SZ_D) * 2;  // bytes

    if (ws_size >= need_fast) {
        bf16* xb    = (bf16*)d_ws;          // x cast          (SZ_D)
        bf16* wbuf  = xb    + SZ_D;         // weight cast     (SZ_D, reused serially)
        bf16* q_ws  = wbuf  + SZ_D;         // Q               (SZ_D)
        bf16* kv_ws = q_ws  + SZ_D;         // merged K|V      (2*SZ_KV)
        bf16* vt_ws = kv_ws + 2 * SZ_KV;    // V^T             (SZ_KV)
        bf16* ao_ws = vt_ws + SZ_KV;        // attn out        (SZ_D)

        // cast x and wq together, then Q-proj
        cast2_kernel<<<2 * (SZ_D / 2048), blk, 0, stream>>>(x, xb, wq, wbuf,
                                                            (int)(SZ_D / 2048));
        gemm_nt_256<bf16><<<dim3(16, 16), dim3(512), 0, stream>>>(xb, wbuf, q_ws, 4096, 4096, 4096);

        // cast wk+wv stacked (rows 0-1023 = wk, 1024-2047 = wv), merged KV-proj
        cast2_kernel<<<2 * (SZ_KV / 2048), blk, 0, stream>>>(wk, wbuf, wv, wbuf + SZ_KV,
                                                             (int)(SZ_KV / 2048));
        gemm_nt_fast<bf16><<<dim3(16, 32), blk, 0, stream>>>(xb, wbuf, kv_ws, 4096, 2048, 4096);

        // fused K-RoPE + V-transpose (Q-rope fused into attn)
        rope_tr_kernel<<<(B_ * S_ * KVH_ * 64) / 256 + 1024, blk, 0, stream>>>(
            kv_ws, vt_ws, cosb, sinb);

        attn_kernel<<<dim3(32, 16, 2), dim3(512), 0, stream>>>(
            q_ws, kv_ws, vt_ws, ao_ws, cosb, sinb);

        cast_kernel<<<SZ_D / 2048, blk, 0, stream>>>(wo, wbuf);
        gemm_nt_256<float><<<dim3(16, 16), dim3(512), 0, stream>>>(ao_ws, wbuf, out, 4096, 4096, 4096);
    } else {
        // fallback: slow GEMMs straight from f32 inputs (fits in ~92 MB ws)
        bf16* q_ws  = (bf16*)d_ws;
        bf16* kv_ws = q_ws  + SZ_D;
        bf16* vt_ws = kv_ws + 2 * SZ_KV;
        bf16* ao_ws = vt_ws + SZ_KV;

        gemm_nt<float, float, bf16><<<dim3(32, 32), blk, 0, stream>>>(x, wq, q_ws, 4096, 4096, 4096, 4096);
        gemm_nt<float, float, bf16><<<dim3(8, 32),  blk, 0, stream>>>(x, wk, kv_ws, 4096, 1024, 4096, KVSTR);
        gemm_nt<float, float, bf16><<<dim3(8, 32),  blk, 0, stream>>>(x, wv, kv_ws + 1024, 4096, 1024, 4096, KVSTR);

        rope_tr_kernel<<<(B_ * S_ * KVH_ * 64) / 256 + 1024, blk, 0, stream>>>(
            kv_ws, vt_ws, cosb, sinb);

        attn_kernel<<<dim3(32, 16, 2), dim3(512), 0, stream>>>(
            q_ws, kv_ws, vt_ws, ao_ws, cosb, sinb);

        gemm_nt<bf16, float, float><<<dim3(32, 32), blk, 0, stream>>>(ao_ws, wo, out, 4096, 4096, 4096, 4096);
    }
}

// Round 15
// 662.473 us; speedup vs baseline: 1.0097x; 1.0066x over previous
//
#include <hip/hip_runtime.h>
#include <hip/hip_bf16.h>

// Problem constants
#define B_  2
#define S_  2048
#define D_  4096
#define H_  32
#define KVH_ 8
#define HD_ 128
#define WIN_ 1024
#define KVSTR 2048   // merged KV row stride (K cols 0-1023, V cols 1024-2047)

typedef __attribute__((ext_vector_type(8))) __bf16 bf16x8;
typedef __attribute__((ext_vector_type(4))) float f32x4;
using bf16 = __hip_bfloat16;

typedef const __attribute__((address_space(1))) void* gas_ptr;
typedef __attribute__((address_space(3))) void* las_ptr;

// async global->LDS, 16B per lane; lds dest = (wave-uniform) l + lane*16
__device__ __forceinline__ void gload16(const void* g, void* l) {
    __builtin_amdgcn_global_load_lds((gas_ptr)g, (las_ptr)l, 16, 0, 0);
}

__device__ __forceinline__ bf16x8 load8(const bf16* p) {
    return *reinterpret_cast<const bf16x8*>(p);
}
__device__ __forceinline__ bf16x8 cvt8(const bf16* p) {
    return *reinterpret_cast<const bf16x8*>(p);
}
__device__ __forceinline__ bf16x8 cvt8(const float* p) {
    const float4* q = reinterpret_cast<const float4*>(p);
    float4 a = q[0], b = q[1];
    bf16x8 r;
    r[0] = (__bf16)a.x; r[1] = (__bf16)a.y; r[2] = (__bf16)a.z; r[3] = (__bf16)a.w;
    r[4] = (__bf16)b.x; r[5] = (__bf16)b.y; r[6] = (__bf16)b.z; r[7] = (__bf16)b.w;
    return r;
}
__device__ __forceinline__ void store1(float* p, float v) { *p = v; }
__device__ __forceinline__ void store1(bf16* p, float v) { *p = __float2bfloat16(v); }

#define GBAR()  __builtin_amdgcn_s_barrier()
#define SCB0()  __builtin_amdgcn_sched_barrier(0)
#define LGKM0() do { asm volatile("s_waitcnt lgkmcnt(0)" ::: "memory"); \
                     __builtin_amdgcn_sched_barrier(0); } while (0)
#define VMC(n)  do { asm volatile("s_waitcnt vmcnt(" #n ")" ::: "memory"); \
                     __builtin_amdgcn_sched_barrier(0); } while (0)

// ---------------------------------------------------------------------------
// f32 -> bf16 cast helpers
// ---------------------------------------------------------------------------
__device__ __forceinline__ void cast8_body(const float* in, bf16* out, long base) {
    long i = (base * 256 + threadIdx.x) * 8;
    const float4* p = reinterpret_cast<const float4*>(in + i);
    float4 a = p[0], b = p[1];
    bf16x8 r;
    r[0] = (__bf16)a.x; r[1] = (__bf16)a.y; r[2] = (__bf16)a.z; r[3] = (__bf16)a.w;
    r[4] = (__bf16)b.x; r[5] = (__bf16)b.y; r[6] = (__bf16)b.z; r[7] = (__bf16)b.w;
    *reinterpret_cast<bf16x8*>(out + i) = r;
}

__global__ __launch_bounds__(256) void cast_kernel(const float* __restrict__ in,
                                                   bf16* __restrict__ out) {
    cast8_body(in, out, blockIdx.x);
}

// two casts in one launch: blocks [0,n0) -> pair0, rest -> pair1
__global__ __launch_bounds__(256) void cast2_kernel(
    const float* __restrict__ in0, bf16* __restrict__ out0,
    const float* __restrict__ in1, bf16* __restrict__ out1, int n0blocks) {
    const bool first = (int)blockIdx.x < n0blocks;
    cast8_body(first ? in0 : in1, first ? out0 : out1,
               first ? (long)blockIdx.x : (long)(blockIdx.x - n0blocks));
}

// ALL five input casts in one launch (tier-1 plan).
// blocks: x [0,8192) wq [8192,16384) wk [16384,18432) wv [18432,20480)
//         wo [20480,28672)
__global__ __launch_bounds__(256) void cast_all_kernel(
    const float* __restrict__ x,  bf16* __restrict__ xb,
    const float* __restrict__ wq, bf16* __restrict__ wqb,
    const float* __restrict__ wk, bf16* __restrict__ wkb,
    const float* __restrict__ wv, bf16* __restrict__ wvb,
    const float* __restrict__ wo, bf16* __restrict__ wob) {
    int bid = blockIdx.x;
    if (bid < 8192)        cast8_body(x,  xb,  bid);
    else if (bid < 16384)  cast8_body(wq, wqb, bid - 8192);
    else if (bid < 18432)  cast8_body(wk, wkb, bid - 16384);
    else if (bid < 20480)  cast8_body(wv, wvb, bid - 18432);
    else                   cast8_body(wo, wob, bid - 20480);
}

// T1 XCD swizzle: requires nwg % 8 == 0 (all our grids: 256, 512).
__device__ __forceinline__ void xcd_swizzle(int& bx, int& by, int nbx, int nby) {
    int flat = bx + nbx * by;
    int nwg  = nbx * nby;
    int cpx  = nwg >> 3;
    int swz  = (flat & 7) * cpx + (flat >> 3);
    bx = swz % nbx;
    by = swz / nbx;
}

// ---------------------------------------------------------------------------
// 256x256 deep-pipelined NT GEMM (bf16 in): C = A[M,K] @ B[N,K]^T.
// 8 waves (2Mx4N), BK=64, 2-deep LDS dbuf (128 KiB), 4 phases/K-tile.
// Counted vmcnt(6). NOTE: 128 KiB LDS -> 1 block/CU; grid must be <=256
// (round-11 lesson). [verified rounds 2/5/6/7/8/10/12/14]
// ---------------------------------------------------------------------------
template <typename TC>
__global__ __launch_bounds__(512, 2) void gemm_nt_256(
    const bf16* __restrict__ A, const bf16* __restrict__ Bm,
    TC* __restrict__ C, int M, int N, int K) {
    // [buf][0=A,1=B][256 rows x 64 cols]
    __shared__ __bf16 lds[2][2][256 * 64];   // 128 KiB

    const int tid  = threadIdx.x;
    const int wave = tid >> 6;          // 0..7
    const int lane = tid & 63;
    const int col  = lane & 15;
    const int quad = lane >> 4;
    const int c7   = col & 7;
    const int wmi  = wave >> 2;         // 0..1  (M half)
    const int wni  = wave & 3;          // 0..3  (N quarter)
    int bx = blockIdx.x, by = blockIdx.y;
    xcd_swizzle(bx, by, gridDim.x, gridDim.y);
    const long m0  = (long)by * 256;
    const long n0  = (long)bx * 256;
    const int  nt  = K >> 6;            // K-tiles

    f32x4 zero = {0.f, 0.f, 0.f, 0.f};
    f32x4 acc[8][4];
#pragma unroll
    for (int i = 0; i < 8; i++)
#pragma unroll
        for (int j = 0; j < 4; j++) acc[i][j] = zero;

    // staging: load j covers rows j*64 + wave*8 .. +7 (this wave's slice)
    long gA[4], gB[4];
    int  lofs[4];
#pragma unroll
    for (int j = 0; j < 4; j++) {
        int r  = j * 64 + wave * 8 + (lane >> 3);
        int cg = (lane & 7) ^ (r & 7);          // pre-swizzled source chunk
        gA[j]   = (m0 + r) * (long)K + cg * 8;
        gB[j]   = (n0 + r) * (long)K + cg * 8;
        lofs[j] = (j * 64 + wave * 8) * 128;    // bytes; HW adds lane*16
    }

    // ---- prologue: tile0 full (8) + tile1 B(4)+A-lo(2) = 14 loads ----
#pragma unroll
    for (int j = 0; j < 4; j++) {
        gload16(A  + gA[j], (char*)lds[0][0] + lofs[j]);
        gload16(Bm + gB[j], (char*)lds[0][1] + lofs[j]);
    }
    if (nt > 1) {
#pragma unroll
        for (int j = 0; j < 4; j++)
            gload16(Bm + gB[j] + 64, (char*)lds[1][1] + lofs[j]);
        gload16(A + gA[0] + 64, (char*)lds[1][0] + lofs[0]);
        gload16(A + gA[2] + 64, (char*)lds[1][0] + lofs[2]);
        VMC(6);
    } else {
        VMC(0);
    }
    GBAR();

#define RDA_(dst, mf, ks) \
    dst = *reinterpret_cast<const bf16x8*>(Ab + (wmi * 128 + (mf) * 16 + col) * 128 \
                                              + ((((ks) << 2) + quad) ^ c7) * 16)
#define MFMA16(mb) \
    do { \
        _Pragma("unroll") \
        for (int ks = 0; ks < 2; ks++) { \
            _Pragma("unroll") \
            for (int nf = 0; nf < 4; nf++) { \
                acc[mb][nf]     = __builtin_amdgcn_mfma_f32_16x16x32_bf16( \
                    a[0][ks], bfr[nf][ks], acc[mb][nf], 0, 0, 0); \
                acc[mb + 1][nf] = __builtin_amdgcn_mfma_f32_16x16x32_bf16( \
                    a[1][ks], bfr[nf][ks], acc[mb + 1][nf], 0, 0, 0); \
            } \
        } \
    } while (0)

    for (int t = 0; t < nt; ++t) {
        const int cur = t & 1;
        const char* Ab = (const char*)lds[cur][0];
        const char* Bb = (const char*)lds[cur][1];
        char* An2 = (char*)lds[cur ^ 1][0];   // tile t+1 A (finish hi rows)
        char* Ac2 = (char*)lds[cur][0];       // tile t+2 A (parity == t)
        char* Bc2 = (char*)lds[cur][1];       // tile t+2 B

        // ---------------- P1 ----------------
        bf16x8 bfr[4][2];
#pragma unroll
        for (int nf = 0; nf < 4; nf++)
#pragma unroll
            for (int ks = 0; ks < 2; ks++)
                bfr[nf][ks] = *reinterpret_cast<const bf16x8*>(
                    Bb + (wni * 64 + nf * 16 + col) * 128 + (((ks << 2) + quad) ^ c7) * 16);
        bf16x8 a[2][2];
        RDA_(a[0][0], 0, 0); RDA_(a[0][1], 0, 1);
        RDA_(a[1][0], 1, 0); RDA_(a[1][1], 1, 1);
        if (t + 1 < nt) {                      // stage A hi-rows of tile t+1
            long ko = (long)(t + 1) * 64;
            gload16(A + gA[1] + ko, An2 + lofs[1]);
            gload16(A + gA[3] + ko, An2 + lofs[3]);
        }
        GBAR();
        LGKM0();
        __builtin_amdgcn_s_setprio(1);
        MFMA16(0);
        __builtin_amdgcn_s_setprio(0);
        GBAR();

        // ---------------- P2 ----------------
        RDA_(a[0][0], 2, 0); RDA_(a[0][1], 2, 1);
        RDA_(a[1][0], 3, 0); RDA_(a[1][1], 3, 1);
        if (t + 2 < nt) {                      // stage B of tile t+2
            long ko = (long)(t + 2) * 64;
#pragma unroll
            for (int j = 0; j < 4; j++)
                gload16(Bm + gB[j] + ko, Bc2 + lofs[j]);
        }
        GBAR();
        LGKM0();
        __builtin_amdgcn_s_setprio(1);
        MFMA16(2);
        __builtin_amdgcn_s_setprio(0);
        GBAR();

        // ---------------- P3 ----------------
        RDA_(a[0][0], 4, 0); RDA_(a[0][1], 4, 1);
        RDA_(a[1][0], 5, 0); RDA_(a[1][1], 5, 1);
        if (t + 2 < nt) {                      // stage A lo-rows of tile t+2
            long ko = (long)(t + 2) * 64;
            gload16(A + gA[0] + ko, Ac2 + lofs[0]);
            gload16(A + gA[2] + ko, Ac2 + lofs[2]);
        }
        GBAR();
        LGKM0();
        __builtin_amdgcn_s_setprio(1);
        MFMA16(4);
        __builtin_amdgcn_s_setprio(0);
        GBAR();

        // ---------------- P4 ----------------
        RDA_(a[0][0], 6, 0); RDA_(a[0][1], 6, 1);
        RDA_(a[1][0], 7, 0); RDA_(a[1][1], 7, 1);
        LGKM0();
        __builtin_amdgcn_s_setprio(1);
        MFMA16(6);
        __builtin_amdgcn_s_setprio(0);
        if (t + 2 < nt) { VMC(6); } else { VMC(0); }
        GBAR();
    }

    // C/D layout: col=lane&15, row=quad*4+reg  [m89/m91 verified]
#pragma unroll
    for (int mf = 0; mf < 8; mf++) {
#pragma unroll
        for (int nf = 0; nf < 4; nf++) {
            long row = m0 + wmi * 128 + mf * 16 + quad * 4;
            long cc  = n0 + wni * 64 + nf * 16 + col;
#pragma unroll
            for (int r = 0; r < 4; r++)
                store1(&C[(row + r) * (long)N + cc], acc[mf][nf][r]);
        }
    }
}

// ---------------------------------------------------------------------------
// FAST NT GEMM (bf16 in): C[M,N] = A[M,K] @ B[N,K]^T, f32 accumulate.
// 128x128 tile, BK=64 — used for the MERGED K+V projection (N=2048).
// ---------------------------------------------------------------------------
template <typename TC>
__global__ __launch_bounds__(256) void gemm_nt_fast(
    const bf16* __restrict__ A, const bf16* __restrict__ Bm,
    TC* __restrict__ C, int M, int N, int K) {
    __shared__ __bf16 As[128 * 64];   // 16 KB, swizzled, unpadded
    __shared__ __bf16 Bs[128 * 64];

    const int tid  = threadIdx.x;
    const int wave = tid >> 6;
    const int lane = tid & 63;
    const int col  = lane & 15;
    const int quad = lane >> 4;
    const int c7   = col & 7;
    const int wm   = (wave >> 1) * 64;
    const int wn   = (wave & 1) * 64;
    int bx = blockIdx.x, by = blockIdx.y;
    xcd_swizzle(bx, by, gridDim.x, gridDim.y);
    const long m0  = (long)by * 128;
    const long n0  = (long)bx * 128;

    f32x4 zero = {0.f, 0.f, 0.f, 0.f};
    f32x4 acc[4][4];
#pragma unroll
    for (int i = 0; i < 4; i++)
#pragma unroll
        for (int j = 0; j < 4; j++) acc[i][j] = zero;

    long goffA[4], goffB[4];
    int  loff[4];
#pragma unroll
    for (int i = 0; i < 4; i++) {
        int r  = (wave * 4 + i) * 8 + (lane >> 3);
        int cg = (lane & 7) ^ (r & 7);
        goffA[i] = (m0 + r) * (long)K + cg * 8;
        goffB[i] = (n0 + r) * (long)K + cg * 8;
        loff[i]  = (wave * 4 + i) * 1024;   // bytes; HW adds lane*16
    }

    for (int kt = 0; kt < K; kt += 64) {
#pragma unroll
        for (int i = 0; i < 4; i++) {
            gload16(A + goffA[i] + kt, (char*)As + loff[i]);
            gload16(Bm + goffB[i] + kt, (char*)Bs + loff[i]);
        }
        __syncthreads();

        bf16x8 af[2][4], bfv[2][4];
#pragma unroll
        for (int ks = 0; ks < 2; ks++) {
#pragma unroll
            for (int mt = 0; mt < 4; mt++) {
                int row = wm + mt * 16 + col;
                af[ks][mt] = *reinterpret_cast<const bf16x8*>(
                    (const char*)As + row * 128 + (((ks << 2) + quad) ^ c7) * 16);
            }
#pragma unroll
            for (int nt = 0; nt < 4; nt++) {
                int row = wn + nt * 16 + col;
                bfv[ks][nt] = *reinterpret_cast<const bf16x8*>(
                    (const char*)Bs + row * 128 + (((ks << 2) + quad) ^ c7) * 16);
            }
        }
#pragma unroll
        for (int ks = 0; ks < 2; ks++)
#pragma unroll
            for (int mt = 0; mt < 4; mt++)
#pragma unroll
                for (int nt = 0; nt < 4; nt++)
                    acc[mt][nt] = __builtin_amdgcn_mfma_f32_16x16x32_bf16(
                        af[ks][mt], bfv[ks][nt], acc[mt][nt], 0, 0, 0);
        __syncthreads();
    }

#pragma unroll
    for (int mt = 0; mt < 4; mt++) {
#pragma unroll
        for (int nt = 0; nt < 4; nt++) {
            long row = m0 + wm + mt * 16 + quad * 4;
            long cc  = n0 + wn + nt * 16 + col;
#pragma unroll
            for (int r = 0; r < 4; r++)
                store1(&C[(row + r) * (long)N + cc], acc[mt][nt][r]);
        }
    }
}

// ---------------------------------------------------------------------------
// SLOW NT GEMM (f32/bf16 in, convert at staging) — fallback if ws too small.
// ---------------------------------------------------------------------------
template <typename TA, typename TB, typename TC>
__global__ __launch_bounds__(256) void gemm_nt(
    const TA* __restrict__ A, const TB* __restrict__ Bm,
    TC* __restrict__ C, int M, int N, int K, int ldc) {
    __shared__ __bf16 As[128 * 40];
    __shared__ __bf16 Bs[128 * 40];

    const int tid  = threadIdx.x;
    const int wave = tid >> 6;
    const int lane = tid & 63;
    const int col  = lane & 15;
    const int quad = lane >> 4;
    const int wm   = (wave >> 1) * 64;
    const int wn   = (wave & 1) * 64;
    const long m0  = (long)blockIdx.y * 128;
    const long n0  = (long)blockIdx.x * 128;

    f32x4 zero = {0.f, 0.f, 0.f, 0.f};
    f32x4 acc[4][4];
#pragma unroll
    for (int i = 0; i < 4; i++)
#pragma unroll
        for (int j = 0; j < 4; j++) acc[i][j] = zero;

    const int srow = tid >> 2;
    const int sch  = (tid & 3) * 8;

    for (int kt = 0; kt < K; kt += 32) {
        bf16x8 av0 = cvt8(A + (m0 + srow)      * (long)K + kt + sch);
        bf16x8 av1 = cvt8(A + (m0 + srow + 64) * (long)K + kt + sch);
        bf16x8 bv0 = cvt8(Bm + (n0 + srow)      * (long)K + kt + sch);
        bf16x8 bv1 = cvt8(Bm + (n0 + srow + 64) * (long)K + kt + sch);
        *reinterpret_cast<bf16x8*>(&As[srow * 40 + sch])        = av0;
        *reinterpret_cast<bf16x8*>(&As[(srow + 64) * 40 + sch]) = av1;
        *reinterpret_cast<bf16x8*>(&Bs[srow * 40 + sch])        = bv0;
        *reinterpret_cast<bf16x8*>(&Bs[(srow + 64) * 40 + sch]) = bv1;
        __syncthreads();

        bf16x8 af[4], bfv[4];
#pragma unroll
        for (int mt = 0; mt < 4; mt++)
            af[mt] = *reinterpret_cast<const bf16x8*>(&As[(wm + mt * 16 + col) * 40 + quad * 8]);
#pragma unroll
        for (int nt = 0; nt < 4; nt++)
            bfv[nt] = *reinterpret_cast<const bf16x8*>(&Bs[(wn + nt * 16 + col) * 40 + quad * 8]);
#pragma unroll
        for (int mt = 0; mt < 4; mt++)
#pragma unroll
            for (int nt = 0; nt < 4; nt++)
                acc[mt][nt] = __builtin_amdgcn_mfma_f32_16x16x32_bf16(
                    af[mt], bfv[nt], acc[mt][nt], 0, 0, 0);
        __syncthreads();
    }

#pragma unroll
    for (int mt = 0; mt < 4; mt++) {
#pragma unroll
        for (int nt = 0; nt < 4; nt++) {
            long row = m0 + wm + mt * 16 + quad * 4;
            long cc  = n0 + wn + nt * 16 + col;
#pragma unroll
            for (int r = 0; r < 4; r++)
                store1(&C[(row + r) * (long)ldc + cc], acc[mt][nt][r]);
        }
    }
}

// ---------------------------------------------------------------------------
// FUSED K-RoPE + V-transpose, one launch. Blocks [0, NROPE) rope the K part
// of kv (cols 0-1023); blocks [NROPE, NROPE+1024) transpose V (cols 1024+)
// into vt. Disjoint data -> no ordering hazard within the launch.
// ---------------------------------------------------------------------------
__global__ __launch_bounds__(256) void rope_tr_kernel(
    bf16* __restrict__ kv, bf16* __restrict__ vt,
    const float* __restrict__ cosb, const float* __restrict__ sinb) {
    const int NROPE = (B_ * S_ * KVH_ * 64) / 256;   // 8192 blocks
    __shared__ __bf16 tile[64][72];
    if ((int)blockIdx.x < NROPE) {
        int idx = blockIdx.x * 256 + threadIdx.x;
        int pair = idx & 63;
        int rest = idx >> 6;
        int hh   = rest % KVH_;
        int tok  = rest / KVH_;
        int s    = tok & (S_ - 1);
        long base = (long)tok * KVSTR + hh * HD_ + pair * 2;
        float c  = cosb[s * 64 + pair];
        float sn = sinb[s * 64 + pair];
        float t0 = __bfloat162float(kv[base]);
        float t1 = __bfloat162float(kv[base + 1]);
        kv[base]     = __float2bfloat16(t0 * c - t1 * sn);
        kv[base + 1] = __float2bfloat16(t0 * sn + t1 * c);
    } else {
        int bid = blockIdx.x - NROPE;        // 0..1023
        const int s0 = (bid & 31) * 64;
        const int d0 = ((bid >> 5) & 15) * 64;
        const int b  = bid >> 9;
        const int tid = threadIdx.x;
        const int tr  = tid >> 3;
        const int c8  = (tid & 7) * 8;
#pragma unroll
        for (int p = 0; p < 2; p++) {
            int srow = tr + p * 32;
            bf16x8 val = load8(kv + ((long)(b * S_ + s0 + srow)) * KVSTR + 1024 + d0 + c8);
            *reinterpret_cast<bf16x8*>(&tile[srow][c8]) = val;
        }
        __syncthreads();
#pragma unroll
        for (int p = 0; p < 2; p++) {
            int dd = tr + p * 32;
            bf16x8 ov;
#pragma unroll
            for (int j = 0; j < 8; j++) ov[j] = tile[c8 + j][dd];
            *reinterpret_cast<bf16x8*>(vt + ((long)(b * 1024 + d0 + dd)) * S_ + s0 + c8) = ov;
        }
    }
}

// ---------------------------------------------------------------------------
// Windowed flash attention v8 (verified rounds 10/12/14): GQA head-pairing,
// depth-1 T14 reg prefetch, fused Q-RoPE at fragment load. Merged-KV reads.
// grid (S/64, H/2, B), 512 thr.
// ---------------------------------------------------------------------------
__global__ __launch_bounds__(512, 4) void attn_kernel(
    const bf16* __restrict__ q, const bf16* __restrict__ kv,
    const bf16* __restrict__ vt, bf16* __restrict__ o,
    const float* __restrict__ cosb, const float* __restrict__ sinb) {
    const int qb  = blockIdx.x;
    const int hp  = blockIdx.y;          // head pair 0..15
    const int b   = blockIdx.z;
    const int tid = threadIdx.x;
    const int wave = tid >> 6;           // 0..7
    const int lane = tid & 63;
    const int col  = lane & 15;
    const int quad = lane >> 4;
    const int h    = hp * 2 + (wave >> 2);   // this wave's head
    const int wq4  = wave & 3;               // q-row group within head
    const int kvh  = hp >> 1;                // == h>>2 (pair shares kv-head)
    const int i0   = qb * 64;
    const float scale = 0.08838834764831845f;  // 1/sqrt(128)

    __shared__ __bf16 Ks[64 * 128];   // 16 KB: slot(r, cl16) = glob chunk cl^(r&15)
    __shared__ __bf16 Vs[128 * 64];   // 16 KB: slot(d, cl8)  = glob chunk cl^(d&7)
    __shared__ __bf16 Pl[8][16 * 72]; // per-wave P tile (padded, plain ds)

    // Q A-fragments in regs with fused RoPE (verified round 10).
    const int srow = i0 + wq4 * 16 + col;    // sequence position of this lane's row
    bf16x8 qa[4];
    {
        const bf16* qptr = q + ((long)(b * S_ + srow)) * (H_ * HD_) + h * HD_ + quad * 8;
#pragma unroll
        for (int ks = 0; ks < 4; ks++) {
            bf16x8 v = load8(qptr + ks * 32);
            float4 c4 = *reinterpret_cast<const float4*>(
                cosb + (long)srow * 64 + quad * 4 + ks * 16);
            float4 s4 = *reinterpret_cast<const float4*>(
                sinb + (long)srow * 64 + quad * 4 + ks * 16);
            bf16x8 r;
            float t0, t1;
            t0 = (float)v[0]; t1 = (float)v[1];
            r[0] = (__bf16)(t0 * c4.x - t1 * s4.x); r[1] = (__bf16)(t0 * s4.x + t1 * c4.x);
            t0 = (float)v[2]; t1 = (float)v[3];
            r[2] = (__bf16)(t0 * c4.y - t1 * s4.y); r[3] = (__bf16)(t0 * s4.y + t1 * c4.y);
            t0 = (float)v[4]; t1 = (float)v[5];
            r[4] = (__bf16)(t0 * c4.z - t1 * s4.z); r[5] = (__bf16)(t0 * s4.z + t1 * c4.z);
            t0 = (float)v[6]; t1 = (float)v[7];
            r[6] = (__bf16)(t0 * c4.w - t1 * s4.w); r[7] = (__bf16)(t0 * s4.w + t1 * c4.w);
            qa[ks] = r;
        }
    }

    // staging: 8 waves x 2 loads each for K and V (1KB chunks, wave*2+i)
    long gK[2], gV[2];
    int  lK[2], lV[2];
#pragma unroll
    for (int i = 0; i < 2; i++) {
        int ck  = wave * 2 + i;                             // 0..15
        int rK  = ck * 4 + (lane >> 4);                     // 0..63
        int cgK = (lane & 15) ^ (rK & 15);
        gK[i] = ((long)(b * S_) + rK) * KVSTR + kvh * HD_ + cgK * 8;
        lK[i] = ck * 1024;
        int rV  = ck * 8 + (lane >> 3);                     // 0..127
        int cgV = (lane & 7) ^ (rV & 7);
        gV[i] = ((long)(b * 1024) + kvh * HD_ + rV) * (long)S_ + cgV * 8;
        lV[i] = ck * 1024;
    }

    f32x4 zero = {0.f, 0.f, 0.f, 0.f};
    f32x4 oacc[8];
#pragma unroll
    for (int i = 0; i < 8; i++) oacc[i] = zero;
    float lsum[4] = {0.f, 0.f, 0.f, 0.f};

    const int kb0 = (qb >= 16) ? (qb - 16) : 0;

    // prologue: load tile kb0 into registers (16B/lane x 4)
    bf16x8 kreg[2], vreg[2];
#pragma unroll
    for (int i = 0; i < 2; i++) {
        kreg[i] = *reinterpret_cast<const bf16x8*>(kv + gK[i] + (long)kb0 * 64 * KVSTR);
        vreg[i] = *reinterpret_cast<const bf16x8*>(vt + gV[i] + kb0 * 64);
    }

    for (int kb = kb0; kb <= qb; kb++) {
        GBAR();              // (A) all waves done reading the previous tile
        SCB0();
        // write tile kb (registers -> LDS, same layout gload_lds produced)
#pragma unroll
        for (int i = 0; i < 2; i++) {
            *reinterpret_cast<bf16x8*>((char*)Ks + lK[i] + lane * 16) = kreg[i];
            *reinterpret_cast<bf16x8*>((char*)Vs + lV[i] + lane * 16) = vreg[i];
        }
        LGKM0();             // my ds_writes retired
        GBAR();              // (B) all waves' tile-kb data visible
        SCB0();
        // T14: issue next tile's loads NOW — latency hides under compute(kb)
        if (kb < qb) {
#pragma unroll
            for (int i = 0; i < 2; i++) {
                kreg[i] = *reinterpret_cast<const bf16x8*>(
                    kv + gK[i] + (long)(kb + 1) * 64 * KVSTR);
                vreg[i] = *reinterpret_cast<const bf16x8*>(
                    vt + gV[i] + (kb + 1) * 64);
            }
            SCB0();          // pin the issue point before the compute body
        }

        // S = Q K^T
        f32x4 sfr[4];
        __builtin_amdgcn_s_setprio(1);
#pragma unroll
        for (int nt = 0; nt < 4; nt++) {
            f32x4 s = zero;
            int row = nt * 16 + col;
#pragma unroll
            for (int ks = 0; ks < 4; ks++) {
                bf16x8 bfv = *reinterpret_cast<const bf16x8*>(
                    (const char*)Ks + row * 256 + (((ks << 2) + quad) ^ col) * 16);
                s = __builtin_amdgcn_mfma_f32_16x16x32_bf16(qa[ks], bfv, s, 0, 0, 0);
            }
            sfr[nt] = s;
        }
        __builtin_amdgcn_s_setprio(0);
        // mask + exp + P -> per-wave LDS
#pragma unroll
        for (int nt = 0; nt < 4; nt++) {
            int j = kb * 64 + nt * 16 + col;
#pragma unroll
            for (int r = 0; r < 4; r++) {
                int i = i0 + wq4 * 16 + quad * 4 + r;
                float p = 0.f;
                if (j <= i && (i - j) < WIN_) p = __expf(sfr[nt][r] * scale);
                lsum[r] += p;
                Pl[wave][(quad * 4 + r) * 72 + nt * 16 + col] = __float2bfloat16(p);
            }
        }
        // O += P V
        __builtin_amdgcn_s_setprio(1);
#pragma unroll
        for (int ks2 = 0; ks2 < 2; ks2++) {
            bf16x8 pa = *reinterpret_cast<const bf16x8*>(
                &Pl[wave][col * 72 + ks2 * 32 + quad * 8]);
#pragma unroll
            for (int nt2 = 0; nt2 < 8; nt2++) {
                int d = nt2 * 16 + col;
                bf16x8 vb = *reinterpret_cast<const bf16x8*>(
                    (const char*)Vs + d * 128 + ((((ks2 << 2) + quad)) ^ (col & 7)) * 16);
                oacc[nt2] = __builtin_amdgcn_mfma_f32_16x16x32_bf16(
                    pa, vb, oacc[nt2], 0, 0, 0);
            }
        }
        __builtin_amdgcn_s_setprio(0);
    }

    // lsum across the 16 col-lanes of each quad group
#pragma unroll
    for (int m = 1; m < 16; m <<= 1) {
#pragma unroll
        for (int r = 0; r < 4; r++) lsum[r] += __shfl_xor(lsum[r], m, 64);
    }

    bf16* op = o + ((long)(b * S_ + i0 + wq4 * 16 + quad * 4)) * (H_ * HD_) + h * HD_;
#pragma unroll
    for (int nt2 = 0; nt2 < 8; nt2++) {
#pragma unroll
        for (int r = 0; r < 4; r++)
            op[(long)r * (H_ * HD_) + nt2 * 16 + col] =
                __float2bfloat16(oacc[nt2][r] / lsum[r]);
    }
}

// ---------------------------------------------------------------------------
extern "C" void kernel_launch(void* const* d_in, const int* in_sizes, int n_in,
                              void* d_out, int out_size, void* d_ws, size_t ws_size,
                              hipStream_t stream) {
    const float* x    = (const float*)d_in[0];
    const float* wq   = (const float*)d_in[1];
    const float* wk   = (const float*)d_in[2];
    const float* wv   = (const float*)d_in[3];
    const float* wo   = (const float*)d_in[4];
    const float* cosb = (const float*)d_in[5];
    const float* sinb = (const float*)d_in[6];
    float* out = (float*)d_out;

    const size_t T   = (size_t)B_ * S_;        // 4096 tokens
    const size_t SZ_D  = T * (H_ * HD_);       // 16.78M elements
    const size_t SZ_KV = T * (KVH_ * HD_);     // 4.19M elements

    dim3 blk(256);
    // tier-1: xb + wqb(=ao) + wkv + wob + q + kv + vt  (all weights up front)
    const size_t need_t1 = (4 * SZ_D + 5 * SZ_KV) * 2;             // ~176 MB
    // tier-2 (verified round-12 plan): xb + wbuf + q + kv + vt + ao
    const size_t need_t2 = (SZ_D * 3 + SZ_KV * 3 + SZ_D) * 2;      // ~159 MB

    if (ws_size >= need_t1) {
        bf16* xb    = (bf16*)d_ws;          // x cast           (SZ_D)
        bf16* wqb   = xb    + SZ_D;         // wq cast; ao aliases after Q-proj
        bf16* wkvb  = wqb   + SZ_D;         // stacked wk|wv    (2*SZ_KV)
        bf16* wob   = wkvb  + 2 * SZ_KV;    // wo cast          (SZ_D)
        bf16* q_ws  = wob   + SZ_D;         // Q                (SZ_D)
        bf16* kv_ws = q_ws  + SZ_D;         // merged K|V       (2*SZ_KV)
        bf16* vt_ws = kv_ws + 2 * SZ_KV;    // V^T              (SZ_KV)
        bf16* ao_ws = wqb;                  // attn out aliases wqb (dead post Q-proj)

        // ONE cast launch for all five inputs
        cast_all_kernel<<<28672, blk, 0, stream>>>(x, xb, wq, wqb, wk, wkvb,
                                                   wv, wkvb + SZ_KV, wo, wob);

        gemm_nt_256<bf16><<<dim3(16, 16), dim3(512), 0, stream>>>(xb, wqb, q_ws, 4096, 4096, 4096);
        gemm_nt_fast<bf16><<<dim3(16, 32), blk, 0, stream>>>(xb, wkvb, kv_ws, 4096, 2048, 4096);

        rope_tr_kernel<<<(B_ * S_ * KVH_ * 64) / 256 + 1024, blk, 0, stream>>>(
            kv_ws, vt_ws, cosb, sinb);

        attn_kernel<<<dim3(32, 16, 2), dim3(512), 0, stream>>>(
            q_ws, kv_ws, vt_ws, ao_ws, cosb, sinb);

        gemm_nt_256<float><<<dim3(16, 16), dim3(512), 0, stream>>>(ao_ws, wob, out, 4096, 4096, 4096);
    } else if (ws_size >= need_t2) {
        // verified round-12 plan
        bf16* xb    = (bf16*)d_ws;          // x cast          (SZ_D)
        bf16* wbuf  = xb    + SZ_D;         // weight cast     (SZ_D, reused serially)
        bf16* q_ws  = wbuf  + SZ_D;         // Q               (SZ_D)
        bf16* kv_ws = q_ws  + SZ_D;         // merged K|V      (2*SZ_KV)
        bf16* vt_ws = kv_ws + 2 * SZ_KV;    // V^T             (SZ_KV)
        bf16* ao_ws = vt_ws + SZ_KV;        // attn out        (SZ_D)

        cast2_kernel<<<2 * (SZ_D / 2048), blk, 0, stream>>>(x, xb, wq, wbuf,
                                                            (int)(SZ_D / 2048));
        gemm_nt_256<bf16><<<dim3(16, 16), dim3(512), 0, stream>>>(xb, wbuf, q_ws, 4096, 4096, 4096);

        cast2_kernel<<<2 * (SZ_KV / 2048), blk, 0, stream>>>(wk, wbuf, wv, wbuf + SZ_KV,
                                                             (int)(SZ_KV / 2048));
        gemm_nt_fast<bf16><<<dim3(16, 32), blk, 0, stream>>>(xb, wbuf, kv_ws, 4096, 2048, 4096);

        rope_tr_kernel<<<(B_ * S_ * KVH_ * 64) / 256 + 1024, blk, 0, stream>>>(
            kv_ws, vt_ws, cosb, sinb);

        attn_kernel<<<dim3(32, 16, 2), dim3(512), 0, stream>>>(
            q_ws, kv_ws, vt_ws, ao_ws, cosb, sinb);

        cast_kernel<<<SZ_D / 2048, blk, 0, stream>>>(wo, wbuf);
        gemm_nt_256<float><<<dim3(16, 16), dim3(512), 0, stream>>>(ao_ws, wbuf, out, 4096, 4096, 4096);
    } else {
        // fallback: slow GEMMs straight from f32 inputs (fits in ~92 MB ws)
        bf16* q_ws  = (bf16*)d_ws;
        bf16* kv_ws = q_ws  + SZ_D;
        bf16* vt_ws = kv_ws + 2 * SZ_KV;
        bf16* ao_ws = vt_ws + SZ_KV;

        gemm_nt<float, float, bf16><<<dim3(32, 32), blk, 0, stream>>>(x, wq, q_ws, 4096, 4096, 4096, 4096);
        gemm_nt<float, float, bf16><<<dim3(8, 32),  blk, 0, stream>>>(x, wk, kv_ws, 4096, 1024, 4096, KVSTR);
        gemm_nt<float, float, bf16><<<dim3(8, 32),  blk, 0, stream>>>(x, wv, kv_ws + 1024, 4096, 1024, 4096, KVSTR);

        rope_tr_kernel<<<(B_ * S_ * KVH_ * 64) / 256 + 1024, blk, 0, stream>>>(
            kv_ws, vt_ws, cosb, sinb);

        attn_kernel<<<dim3(32, 16, 2), dim3(512), 0, stream>>>(
            q_ws, kv_ws, vt_ws, ao_ws, cosb, sinb);

        gemm_nt<bf16, float, float><<<dim3(32, 32), blk, 0, stream>>>(ao_ws, wo, out, 4096, 4096, 4096, 4096);
    }
}

// Round 16
// 658.408 us; speedup vs baseline: 1.0159x; 1.0062x over previous
//
#include <hip/hip_runtime.h>
#include <hip/hip_bf16.h>

// Problem constants
#define B_  2
#define S_  2048
#define D_  4096
#define H_  32
#define KVH_ 8
#define HD_ 128
#define WIN_ 1024
#define KVSTR 2048   // merged KV row stride (K cols 0-1023, V cols 1024-2047)

typedef __attribute__((ext_vector_type(8))) __bf16 bf16x8;
typedef __attribute__((ext_vector_type(4))) float f32x4;
using bf16 = __hip_bfloat16;

typedef const __attribute__((address_space(1))) void* gas_ptr;
typedef __attribute__((address_space(3))) void* las_ptr;

// async global->LDS, 16B per lane; lds dest = (wave-uniform) l + lane*16
__device__ __forceinline__ void gload16(const void* g, void* l) {
    __builtin_amdgcn_global_load_lds((gas_ptr)g, (las_ptr)l, 16, 0, 0);
}

__device__ __forceinline__ bf16x8 load8(const bf16* p) {
    return *reinterpret_cast<const bf16x8*>(p);
}
__device__ __forceinline__ bf16x8 cvt8(const bf16* p) {
    return *reinterpret_cast<const bf16x8*>(p);
}
__device__ __forceinline__ bf16x8 cvt8(const float* p) {
    const float4* q = reinterpret_cast<const float4*>(p);
    float4 a = q[0], b = q[1];
    bf16x8 r;
    r[0] = (__bf16)a.x; r[1] = (__bf16)a.y; r[2] = (__bf16)a.z; r[3] = (__bf16)a.w;
    r[4] = (__bf16)b.x; r[5] = (__bf16)b.y; r[6] = (__bf16)b.z; r[7] = (__bf16)b.w;
    return r;
}
__device__ __forceinline__ void store1(float* p, float v) { *p = v; }
__device__ __forceinline__ void store1(bf16* p, float v) { *p = __float2bfloat16(v); }

#define GBAR()  __builtin_amdgcn_s_barrier()
#define SCB0()  __builtin_amdgcn_sched_barrier(0)
#define LGKM0() do { asm volatile("s_waitcnt lgkmcnt(0)" ::: "memory"); \
                     __builtin_amdgcn_sched_barrier(0); } while (0)
#define VMC(n)  do { asm volatile("s_waitcnt vmcnt(" #n ")" ::: "memory"); \
                     __builtin_amdgcn_sched_barrier(0); } while (0)

// ---------------------------------------------------------------------------
// f32 -> bf16 cast, 8 elements/thread, exact-size launch (n % 2048 == 0)
// ---------------------------------------------------------------------------
__global__ __launch_bounds__(256) void cast_kernel(const float* __restrict__ in,
                                                   bf16* __restrict__ out) {
    long i = ((long)blockIdx.x * 256 + threadIdx.x) * 8;
    const float4* p = reinterpret_cast<const float4*>(in + i);
    float4 a = p[0], b = p[1];
    bf16x8 r;
    r[0] = (__bf16)a.x; r[1] = (__bf16)a.y; r[2] = (__bf16)a.z; r[3] = (__bf16)a.w;
    r[4] = (__bf16)b.x; r[5] = (__bf16)b.y; r[6] = (__bf16)b.z; r[7] = (__bf16)b.w;
    *reinterpret_cast<bf16x8*>(out + i) = r;
}

// two casts in one launch: blocks [0,n0) -> pair0, rest -> pair1
__global__ __launch_bounds__(256) void cast2_kernel(
    const float* __restrict__ in0, bf16* __restrict__ out0,
    const float* __restrict__ in1, bf16* __restrict__ out1, int n0blocks) {
    const bool first = (int)blockIdx.x < n0blocks;
    const float* in = first ? in0 : in1;
    bf16* out = first ? out0 : out1;
    long bid = first ? blockIdx.x : (blockIdx.x - n0blocks);
    long i = (bid * 256 + threadIdx.x) * 8;
    const float4* p = reinterpret_cast<const float4*>(in + i);
    float4 a = p[0], b = p[1];
    bf16x8 r;
    r[0] = (__bf16)a.x; r[1] = (__bf16)a.y; r[2] = (__bf16)a.z; r[3] = (__bf16)a.w;
    r[4] = (__bf16)b.x; r[5] = (__bf16)b.y; r[6] = (__bf16)b.z; r[7] = (__bf16)b.w;
    *reinterpret_cast<bf16x8*>(out + i) = r;
}

// T1 XCD swizzle: requires nwg % 8 == 0 (all our grids: 256, 512).
__device__ __forceinline__ void xcd_swizzle(int& bx, int& by, int nbx, int nby) {
    int flat = bx + nbx * by;
    int nwg  = nbx * nby;
    int cpx  = nwg >> 3;
    int swz  = (flat & 7) * cpx + (flat >> 3);
    bx = swz % nbx;
    by = swz / nbx;
}

// ---------------------------------------------------------------------------
// 256x256 deep-pipelined NT GEMM (bf16 in): C = A[M,K] @ B[N,K]^T.
// 8 waves (2Mx4N), BK=64, 2-deep LDS dbuf (128 KiB), 4 phases/K-tile.
// Counted vmcnt(6). NOTE: 128 KiB LDS -> 1 block/CU; grid must be <=256
// (round-11 lesson). [verified rounds 2/5/6/7/8/10/12/14/15]
// ---------------------------------------------------------------------------
template <typename TC>
__global__ __launch_bounds__(512, 2) void gemm_nt_256(
    const bf16* __restrict__ A, const bf16* __restrict__ Bm,
    TC* __restrict__ C, int M, int N, int K) {
    // [buf][0=A,1=B][256 rows x 64 cols]
    __shared__ __bf16 lds[2][2][256 * 64];   // 128 KiB

    const int tid  = threadIdx.x;
    const int wave = tid >> 6;          // 0..7
    const int lane = tid & 63;
    const int col  = lane & 15;
    const int quad = lane >> 4;
    const int c7   = col & 7;
    const int wmi  = wave >> 2;         // 0..1  (M half)
    const int wni  = wave & 3;          // 0..3  (N quarter)
    int bx = blockIdx.x, by = blockIdx.y;
    xcd_swizzle(bx, by, gridDim.x, gridDim.y);
    const long m0  = (long)by * 256;
    const long n0  = (long)bx * 256;
    const int  nt  = K >> 6;            // K-tiles

    f32x4 zero = {0.f, 0.f, 0.f, 0.f};
    f32x4 acc[8][4];
#pragma unroll
    for (int i = 0; i < 8; i++)
#pragma unroll
        for (int j = 0; j < 4; j++) acc[i][j] = zero;

    // staging: load j covers rows j*64 + wave*8 .. +7 (this wave's slice)
    long gA[4], gB[4];
    int  lofs[4];
#pragma unroll
    for (int j = 0; j < 4; j++) {
        int r  = j * 64 + wave * 8 + (lane >> 3);
        int cg = (lane & 7) ^ (r & 7);          // pre-swizzled source chunk
        gA[j]   = (m0 + r) * (long)K + cg * 8;
        gB[j]   = (n0 + r) * (long)K + cg * 8;
        lofs[j] = (j * 64 + wave * 8) * 128;    // bytes; HW adds lane*16
    }

    // ---- prologue: tile0 full (8) + tile1 B(4)+A-lo(2) = 14 loads ----
#pragma unroll
    for (int j = 0; j < 4; j++) {
        gload16(A  + gA[j], (char*)lds[0][0] + lofs[j]);
        gload16(Bm + gB[j], (char*)lds[0][1] + lofs[j]);
    }
    if (nt > 1) {
#pragma unroll
        for (int j = 0; j < 4; j++)
            gload16(Bm + gB[j] + 64, (char*)lds[1][1] + lofs[j]);
        gload16(A + gA[0] + 64, (char*)lds[1][0] + lofs[0]);
        gload16(A + gA[2] + 64, (char*)lds[1][0] + lofs[2]);
        VMC(6);
    } else {
        VMC(0);
    }
    GBAR();

#define RDA_(dst, mf, ks) \
    dst = *reinterpret_cast<const bf16x8*>(Ab + (wmi * 128 + (mf) * 16 + col) * 128 \
                                              + ((((ks) << 2) + quad) ^ c7) * 16)
#define MFMA16(mb) \
    do { \
        _Pragma("unroll") \
        for (int ks = 0; ks < 2; ks++) { \
            _Pragma("unroll") \
            for (int nf = 0; nf < 4; nf++) { \
                acc[mb][nf]     = __builtin_amdgcn_mfma_f32_16x16x32_bf16( \
                    a[0][ks], bfr[nf][ks], acc[mb][nf], 0, 0, 0); \
                acc[mb + 1][nf] = __builtin_amdgcn_mfma_f32_16x16x32_bf16( \
                    a[1][ks], bfr[nf][ks], acc[mb + 1][nf], 0, 0, 0); \
            } \
        } \
    } while (0)

    for (int t = 0; t < nt; ++t) {
        const int cur = t & 1;
        const char* Ab = (const char*)lds[cur][0];
        const char* Bb = (const char*)lds[cur][1];
        char* An2 = (char*)lds[cur ^ 1][0];   // tile t+1 A (finish hi rows)
        char* Ac2 = (char*)lds[cur][0];       // tile t+2 A (parity == t)
        char* Bc2 = (char*)lds[cur][1];       // tile t+2 B

        // ---------------- P1 ----------------
        bf16x8 bfr[4][2];
#pragma unroll
        for (int nf = 0; nf < 4; nf++)
#pragma unroll
            for (int ks = 0; ks < 2; ks++)
                bfr[nf][ks] = *reinterpret_cast<const bf16x8*>(
                    Bb + (wni * 64 + nf * 16 + col) * 128 + (((ks << 2) + quad) ^ c7) * 16);
        bf16x8 a[2][2];
        RDA_(a[0][0], 0, 0); RDA_(a[0][1], 0, 1);
        RDA_(a[1][0], 1, 0); RDA_(a[1][1], 1, 1);
        if (t + 1 < nt) {                      // stage A hi-rows of tile t+1
            long ko = (long)(t + 1) * 64;
            gload16(A + gA[1] + ko, An2 + lofs[1]);
            gload16(A + gA[3] + ko, An2 + lofs[3]);
        }
        GBAR();
        LGKM0();
        __builtin_amdgcn_s_setprio(1);
        MFMA16(0);
        __builtin_amdgcn_s_setprio(0);
        GBAR();

        // ---------------- P2 ----------------
        RDA_(a[0][0], 2, 0); RDA_(a[0][1], 2, 1);
        RDA_(a[1][0], 3, 0); RDA_(a[1][1], 3, 1);
        if (t + 2 < nt) {                      // stage B of tile t+2
            long ko = (long)(t + 2) * 64;
#pragma unroll
            for (int j = 0; j < 4; j++)
                gload16(Bm + gB[j] + ko, Bc2 + lofs[j]);
        }
        GBAR();
        LGKM0();
        __builtin_amdgcn_s_setprio(1);
        MFMA16(2);
        __builtin_amdgcn_s_setprio(0);
        GBAR();

        // ---------------- P3 ----------------
        RDA_(a[0][0], 4, 0); RDA_(a[0][1], 4, 1);
        RDA_(a[1][0], 5, 0); RDA_(a[1][1], 5, 1);
        if (t + 2 < nt) {                      // stage A lo-rows of tile t+2
            long ko = (long)(t + 2) * 64;
            gload16(A + gA[0] + ko, Ac2 + lofs[0]);
            gload16(A + gA[2] + ko, Ac2 + lofs[2]);
        }
        GBAR();
        LGKM0();
        __builtin_amdgcn_s_setprio(1);
        MFMA16(4);
        __builtin_amdgcn_s_setprio(0);
        GBAR();

        // ---------------- P4 ----------------
        RDA_(a[0][0], 6, 0); RDA_(a[0][1], 6, 1);
        RDA_(a[1][0], 7, 0); RDA_(a[1][1], 7, 1);
        LGKM0();
        __builtin_amdgcn_s_setprio(1);
        MFMA16(6);
        __builtin_amdgcn_s_setprio(0);
        if (t + 2 < nt) { VMC(6); } else { VMC(0); }
        GBAR();
    }

    // C/D layout: col=lane&15, row=quad*4+reg  [m89/m91 verified]
#pragma unroll
    for (int mf = 0; mf < 8; mf++) {
#pragma unroll
        for (int nf = 0; nf < 4; nf++) {
            long row = m0 + wmi * 128 + mf * 16 + quad * 4;
            long cc  = n0 + wni * 64 + nf * 16 + col;
#pragma unroll
            for (int r = 0; r < 4; r++)
                store1(&C[(row + r) * (long)N + cc], acc[mf][nf][r]);
        }
    }
}

// ---------------------------------------------------------------------------
// FAST NT GEMM (bf16 in): C[M,N] = A[M,K] @ B[N,K]^T, f32 accumulate.
// 128x128 tile, BK=64 — used for the MERGED K+V projection (N=2048).
// ---------------------------------------------------------------------------
template <typename TC>
__global__ __launch_bounds__(256) void gemm_nt_fast(
    const bf16* __restrict__ A, const bf16* __restrict__ Bm,
    TC* __restrict__ C, int M, int N, int K) {
    __shared__ __bf16 As[128 * 64];   // 16 KB, swizzled, unpadded
    __shared__ __bf16 Bs[128 * 64];

    const int tid  = threadIdx.x;
    const int wave = tid >> 6;
    const int lane = tid & 63;
    const int col  = lane & 15;
    const int quad = lane >> 4;
    const int c7   = col & 7;
    const int wm   = (wave >> 1) * 64;
    const int wn   = (wave & 1) * 64;
    int bx = blockIdx.x, by = blockIdx.y;
    xcd_swizzle(bx, by, gridDim.x, gridDim.y);
    const long m0  = (long)by * 128;
    const long n0  = (long)bx * 128;

    f32x4 zero = {0.f, 0.f, 0.f, 0.f};
    f32x4 acc[4][4];
#pragma unroll
    for (int i = 0; i < 4; i++)
#pragma unroll
        for (int j = 0; j < 4; j++) acc[i][j] = zero;

    long goffA[4], goffB[4];
    int  loff[4];
#pragma unroll
    for (int i = 0; i < 4; i++) {
        int r  = (wave * 4 + i) * 8 + (lane >> 3);
        int cg = (lane & 7) ^ (r & 7);
        goffA[i] = (m0 + r) * (long)K + cg * 8;
        goffB[i] = (n0 + r) * (long)K + cg * 8;
        loff[i]  = (wave * 4 + i) * 1024;   // bytes; HW adds lane*16
    }

    for (int kt = 0; kt < K; kt += 64) {
#pragma unroll
        for (int i = 0; i < 4; i++) {
            gload16(A + goffA[i] + kt, (char*)As + loff[i]);
            gload16(Bm + goffB[i] + kt, (char*)Bs + loff[i]);
        }
        __syncthreads();

        bf16x8 af[2][4], bfv[2][4];
#pragma unroll
        for (int ks = 0; ks < 2; ks++) {
#pragma unroll
            for (int mt = 0; mt < 4; mt++) {
                int row = wm + mt * 16 + col;
                af[ks][mt] = *reinterpret_cast<const bf16x8*>(
                    (const char*)As + row * 128 + (((ks << 2) + quad) ^ c7) * 16);
            }
#pragma unroll
            for (int nt = 0; nt < 4; nt++) {
                int row = wn + nt * 16 + col;
                bfv[ks][nt] = *reinterpret_cast<const bf16x8*>(
                    (const char*)Bs + row * 128 + (((ks << 2) + quad) ^ c7) * 16);
            }
        }
#pragma unroll
        for (int ks = 0; ks < 2; ks++)
#pragma unroll
            for (int mt = 0; mt < 4; mt++)
#pragma unroll
                for (int nt = 0; nt < 4; nt++)
                    acc[mt][nt] = __builtin_amdgcn_mfma_f32_16x16x32_bf16(
                        af[ks][mt], bfv[ks][nt], acc[mt][nt], 0, 0, 0);
        __syncthreads();
    }

#pragma unroll
    for (int mt = 0; mt < 4; mt++) {
#pragma unroll
        for (int nt = 0; nt < 4; nt++) {
            long row = m0 + wm + mt * 16 + quad * 4;
            long cc  = n0 + wn + nt * 16 + col;
#pragma unroll
            for (int r = 0; r < 4; r++)
                store1(&C[(row + r) * (long)N + cc], acc[mt][nt][r]);
        }
    }
}

// ---------------------------------------------------------------------------
// SLOW NT GEMM (f32/bf16 in, convert at staging) — fallback if ws too small.
// ---------------------------------------------------------------------------
template <typename TA, typename TB, typename TC>
__global__ __launch_bounds__(256) void gemm_nt(
    const TA* __restrict__ A, const TB* __restrict__ Bm,
    TC* __restrict__ C, int M, int N, int K, int ldc) {
    __shared__ __bf16 As[128 * 40];
    __shared__ __bf16 Bs[128 * 40];

    const int tid  = threadIdx.x;
    const int wave = tid >> 6;
    const int lane = tid & 63;
    const int col  = lane & 15;
    const int quad = lane >> 4;
    const int wm   = (wave >> 1) * 64;
    const int wn   = (wave & 1) * 64;
    const long m0  = (long)blockIdx.y * 128;
    const long n0  = (long)blockIdx.x * 128;

    f32x4 zero = {0.f, 0.f, 0.f, 0.f};
    f32x4 acc[4][4];
#pragma unroll
    for (int i = 0; i < 4; i++)
#pragma unroll
        for (int j = 0; j < 4; j++) acc[i][j] = zero;

    const int srow = tid >> 2;
    const int sch  = (tid & 3) * 8;

    for (int kt = 0; kt < K; kt += 32) {
        bf16x8 av0 = cvt8(A + (m0 + srow)      * (long)K + kt + sch);
        bf16x8 av1 = cvt8(A + (m0 + srow + 64) * (long)K + kt + sch);
        bf16x8 bv0 = cvt8(Bm + (n0 + srow)      * (long)K + kt + sch);
        bf16x8 bv1 = cvt8(Bm + (n0 + srow + 64) * (long)K + kt + sch);
        *reinterpret_cast<bf16x8*>(&As[srow * 40 + sch])        = av0;
        *reinterpret_cast<bf16x8*>(&As[(srow + 64) * 40 + sch]) = av1;
        *reinterpret_cast<bf16x8*>(&Bs[srow * 40 + sch])        = bv0;
        *reinterpret_cast<bf16x8*>(&Bs[(srow + 64) * 40 + sch]) = bv1;
        __syncthreads();

        bf16x8 af[4], bfv[4];
#pragma unroll
        for (int mt = 0; mt < 4; mt++)
            af[mt] = *reinterpret_cast<const bf16x8*>(&As[(wm + mt * 16 + col) * 40 + quad * 8]);
#pragma unroll
        for (int nt = 0; nt < 4; nt++)
            bfv[nt] = *reinterpret_cast<const bf16x8*>(&Bs[(wn + nt * 16 + col) * 40 + quad * 8]);
#pragma unroll
        for (int mt = 0; mt < 4; mt++)
#pragma unroll
            for (int nt = 0; nt < 4; nt++)
                acc[mt][nt] = __builtin_amdgcn_mfma_f32_16x16x32_bf16(
                    af[mt], bfv[nt], acc[mt][nt], 0, 0, 0);
        __syncthreads();
    }

#pragma unroll
    for (int mt = 0; mt < 4; mt++) {
#pragma unroll
        for (int nt = 0; nt < 4; nt++) {
            long row = m0 + wm + mt * 16 + quad * 4;
            long cc  = n0 + wn + nt * 16 + col;
#pragma unroll
            for (int r = 0; r < 4; r++)
                store1(&C[(row + r) * (long)ldc + cc], acc[mt][nt][r]);
        }
    }
}

// ---------------------------------------------------------------------------
// FUSED K-RoPE + V-transpose, one launch. Blocks [0, NROPE) rope the K part
// of kv (cols 0-1023); blocks [NROPE, NROPE+1024) transpose V (cols 1024+)
// into vt. Disjoint data -> no ordering hazard within the launch.
// ---------------------------------------------------------------------------
__global__ __launch_bounds__(256) void rope_tr_kernel(
    bf16* __restrict__ kv, bf16* __restrict__ vt,
    const float* __restrict__ cosb, const float* __restrict__ sinb) {
    const int NROPE = (B_ * S_ * KVH_ * 64) / 256;   // 8192 blocks
    __shared__ __bf16 tile[64][72];
    if ((int)blockIdx.x < NROPE) {
        int idx = blockIdx.x * 256 + threadIdx.x;
        int pair = idx & 63;
        int rest = idx >> 6;
        int hh   = rest % KVH_;
        int tok  = rest / KVH_;
        int s    = tok & (S_ - 1);
        long base = (long)tok * KVSTR + hh * HD_ + pair * 2;
        float c  = cosb[s * 64 + pair];
        float sn = sinb[s * 64 + pair];
        float t0 = __bfloat162float(kv[base]);
        float t1 = __bfloat162float(kv[base + 1]);
        kv[base]     = __float2bfloat16(t0 * c - t1 * sn);
        kv[base + 1] = __float2bfloat16(t0 * sn + t1 * c);
    } else {
        int bid = blockIdx.x - NROPE;        // 0..1023
        const int s0 = (bid & 31) * 64;
        const int d0 = ((bid >> 5) & 15) * 64;
        const int b  = bid >> 9;
        const int tid = threadIdx.x;
        const int tr  = tid >> 3;
        const int c8  = (tid & 7) * 8;
#pragma unroll
        for (int p = 0; p < 2; p++) {
            int srow = tr + p * 32;
            bf16x8 val = load8(kv + ((long)(b * S_ + s0 + srow)) * KVSTR + 1024 + d0 + c8);
            *reinterpret_cast<bf16x8*>(&tile[srow][c8]) = val;
        }
        __syncthreads();
#pragma unroll
        for (int p = 0; p < 2; p++) {
            int dd = tr + p * 32;
            bf16x8 ov;
#pragma unroll
            for (int j = 0; j < 8; j++) ov[j] = tile[c8 + j][dd];
            *reinterpret_cast<bf16x8*>(vt + ((long)(b * 1024 + d0 + dd)) * S_ + s0 + c8) = ov;
        }
    }
}

// ---------------------------------------------------------------------------
// Windowed flash attention v8 (verified rounds 10/12/14/15): GQA head-pairing,
// depth-1 T14 reg prefetch, fused Q-RoPE at fragment load. Merged-KV reads.
// grid (S/64, H/2, B), 512 thr.
// ---------------------------------------------------------------------------
__global__ __launch_bounds__(512, 4) void attn_kernel(
    const bf16* __restrict__ q, const bf16* __restrict__ kv,
    const bf16* __restrict__ vt, bf16* __restrict__ o,
    const float* __restrict__ cosb, const float* __restrict__ sinb) {
    const int qb  = blockIdx.x;
    const int hp  = blockIdx.y;          // head pair 0..15
    const int b   = blockIdx.z;
    const int tid = threadIdx.x;
    const int wave = tid >> 6;           // 0..7
    const int lane = tid & 63;
    const int col  = lane & 15;
    const int quad = lane >> 4;
    const int h    = hp * 2 + (wave >> 2);   // this wave's head
    const int wq4  = wave & 3;               // q-row group within head
    const int kvh  = hp >> 1;                // == h>>2 (pair shares kv-head)
    const int i0   = qb * 64;
    const float scale = 0.08838834764831845f;  // 1/sqrt(128)

    __shared__ __bf16 Ks[64 * 128];   // 16 KB: slot(r, cl16) = glob chunk cl^(r&15)
    __shared__ __bf16 Vs[128 * 64];   // 16 KB: slot(d, cl8)  = glob chunk cl^(d&7)
    __shared__ __bf16 Pl[8][16 * 72]; // per-wave P tile (padded, plain ds)

    // Q A-fragments in regs with fused RoPE (verified round 10).
    const int srow = i0 + wq4 * 16 + col;    // sequence position of this lane's row
    bf16x8 qa[4];
    {
        const bf16* qptr = q + ((long)(b * S_ + srow)) * (H_ * HD_) + h * HD_ + quad * 8;
#pragma unroll
        for (int ks = 0; ks < 4; ks++) {
            bf16x8 v = load8(qptr + ks * 32);
            float4 c4 = *reinterpret_cast<const float4*>(
                cosb + (long)srow * 64 + quad * 4 + ks * 16);
            float4 s4 = *reinterpret_cast<const float4*>(
                sinb + (long)srow * 64 + quad * 4 + ks * 16);
            bf16x8 r;
            float t0, t1;
            t0 = (float)v[0]; t1 = (float)v[1];
            r[0] = (__bf16)(t0 * c4.x - t1 * s4.x); r[1] = (__bf16)(t0 * s4.x + t1 * c4.x);
            t0 = (float)v[2]; t1 = (float)v[3];
            r[2] = (__bf16)(t0 * c4.y - t1 * s4.y); r[3] = (__bf16)(t0 * s4.y + t1 * c4.y);
            t0 = (float)v[4]; t1 = (float)v[5];
            r[4] = (__bf16)(t0 * c4.z - t1 * s4.z); r[5] = (__bf16)(t0 * s4.z + t1 * c4.z);
            t0 = (float)v[6]; t1 = (float)v[7];
            r[6] = (__bf16)(t0 * c4.w - t1 * s4.w); r[7] = (__bf16)(t0 * s4.w + t1 * c4.w);
            qa[ks] = r;
        }
    }

    // staging: 8 waves x 2 loads each for K and V (1KB chunks, wave*2+i)
    long gK[2], gV[2];
    int  lK[2], lV[2];
#pragma unroll
    for (int i = 0; i < 2; i++) {
        int ck  = wave * 2 + i;                             // 0..15
        int rK  = ck * 4 + (lane >> 4);                     // 0..63
        int cgK = (lane & 15) ^ (rK & 15);
        gK[i] = ((long)(b * S_) + rK) * KVSTR + kvh * HD_ + cgK * 8;
        lK[i] = ck * 1024;
        int rV  = ck * 8 + (lane >> 3);                     // 0..127
        int cgV = (lane & 7) ^ (rV & 7);
        gV[i] = ((long)(b * 1024) + kvh * HD_ + rV) * (long)S_ + cgV * 8;
        lV[i] = ck * 1024;
    }

    f32x4 zero = {0.f, 0.f, 0.f, 0.f};
    f32x4 oacc[8];
#pragma unroll
    for (int i = 0; i < 8; i++) oacc[i] = zero;
    float lsum[4] = {0.f, 0.f, 0.f, 0.f};

    const int kb0 = (qb >= 16) ? (qb - 16) : 0;

    // prologue: load tile kb0 into registers (16B/lane x 4)
    bf16x8 kreg[2], vreg[2];
#pragma unroll
    for (int i = 0; i < 2; i++) {
        kreg[i] = *reinterpret_cast<const bf16x8*>(kv + gK[i] + (long)kb0 * 64 * KVSTR);
        vreg[i] = *reinterpret_cast<const bf16x8*>(vt + gV[i] + kb0 * 64);
    }

    for (int kb = kb0; kb <= qb; kb++) {
        GBAR();              // (A) all waves done reading the previous tile
        SCB0();
        // write tile kb (registers -> LDS, same layout gload_lds produced)
#pragma unroll
        for (int i = 0; i < 2; i++) {
            *reinterpret_cast<bf16x8*>((char*)Ks + lK[i] + lane * 16) = kreg[i];
            *reinterpret_cast<bf16x8*>((char*)Vs + lV[i] + lane * 16) = vreg[i];
        }
        LGKM0();             // my ds_writes retired
        GBAR();              // (B) all waves' tile-kb data visible
        SCB0();
        // T14: issue next tile's loads NOW — latency hides under compute(kb)
        if (kb < qb) {
#pragma unroll
            for (int i = 0; i < 2; i++) {
                kreg[i] = *reinterpret_cast<const bf16x8*>(
                    kv + gK[i] + (long)(kb + 1) * 64 * KVSTR);
                vreg[i] = *reinterpret_cast<const bf16x8*>(
                    vt + gV[i] + (kb + 1) * 64);
            }
            SCB0();          // pin the issue point before the compute body
        }

        // S = Q K^T
        f32x4 sfr[4];
        __builtin_amdgcn_s_setprio(1);
#pragma unroll
        for (int nt = 0; nt < 4; nt++) {
            f32x4 s = zero;
            int row = nt * 16 + col;
#pragma unroll
            for (int ks = 0; ks < 4; ks++) {
                bf16x8 bfv = *reinterpret_cast<const bf16x8*>(
                    (const char*)Ks + row * 256 + (((ks << 2) + quad) ^ col) * 16);
                s = __builtin_amdgcn_mfma_f32_16x16x32_bf16(qa[ks], bfv, s, 0, 0, 0);
            }
            sfr[nt] = s;
        }
        __builtin_amdgcn_s_setprio(0);
        // mask + exp + P -> per-wave LDS
#pragma unroll
        for (int nt = 0; nt < 4; nt++) {
            int j = kb * 64 + nt * 16 + col;
#pragma unroll
            for (int r = 0; r < 4; r++) {
                int i = i0 + wq4 * 16 + quad * 4 + r;
                float p = 0.f;
                if (j <= i && (i - j) < WIN_) p = __expf(sfr[nt][r] * scale);
                lsum[r] += p;
                Pl[wave][(quad * 4 + r) * 72 + nt * 16 + col] = __float2bfloat16(p);
            }
        }
        // O += P V
        __builtin_amdgcn_s_setprio(1);
#pragma unroll
        for (int ks2 = 0; ks2 < 2; ks2++) {
            bf16x8 pa = *reinterpret_cast<const bf16x8*>(
                &Pl[wave][col * 72 + ks2 * 32 + quad * 8]);
#pragma unroll
            for (int nt2 = 0; nt2 < 8; nt2++) {
                int d = nt2 * 16 + col;
                bf16x8 vb = *reinterpret_cast<const bf16x8*>(
                    (const char*)Vs + d * 128 + ((((ks2 << 2) + quad)) ^ (col & 7)) * 16);
                oacc[nt2] = __builtin_amdgcn_mfma_f32_16x16x32_bf16(
                    pa, vb, oacc[nt2], 0, 0, 0);
            }
        }
        __builtin_amdgcn_s_setprio(0);
    }

    // lsum across the 16 col-lanes of each quad group
#pragma unroll
    for (int m = 1; m < 16; m <<= 1) {
#pragma unroll
        for (int r = 0; r < 4; r++) lsum[r] += __shfl_xor(lsum[r], m, 64);
    }

    bf16* op = o + ((long)(b * S_ + i0 + wq4 * 16 + quad * 4)) * (H_ * HD_) + h * HD_;
#pragma unroll
    for (int nt2 = 0; nt2 < 8; nt2++) {
#pragma unroll
        for (int r = 0; r < 4; r++)
            op[(long)r * (H_ * HD_) + nt2 * 16 + col] =
                __float2bfloat16(oacc[nt2][r] / lsum[r]);
    }
}

// ---------------------------------------------------------------------------
extern "C" void kernel_launch(void* const* d_in, const int* in_sizes, int n_in,
                              void* d_out, int out_size, void* d_ws, size_t ws_size,
                              hipStream_t stream) {
    const float* x    = (const float*)d_in[0];
    const float* wq   = (const float*)d_in[1];
    const float* wk   = (const float*)d_in[2];
    const float* wv   = (const float*)d_in[3];
    const float* wo   = (const float*)d_in[4];
    const float* cosb = (const float*)d_in[5];
    const float* sinb = (const float*)d_in[6];
    float* out = (float*)d_out;

    const size_t T   = (size_t)B_ * S_;        // 4096 tokens
    const size_t SZ_D  = T * (H_ * HD_);       // 16.78M elements
    const size_t SZ_KV = T * (KVH_ * HD_);     // 4.19M elements

    dim3 blk(256);
    // fast path needs: xb + wbuf + q + kv + vt + ao
    const size_t need_fast = (SZ_D * 3 + SZ_KV * 3 + SZ_D) * 2;  // bytes

    if (ws_size >= need_fast) {
        bf16* xb    = (bf16*)d_ws;          // x cast          (SZ_D)
        bf16* wbuf  = xb    + SZ_D;         // weight cast     (SZ_D, reused serially)
        bf16* q_ws  = wbuf  + SZ_D;         // Q               (SZ_D)
        bf16* kv_ws = q_ws  + SZ_D;         // merged K|V      (2*SZ_KV)
        bf16* vt_ws = kv_ws + 2 * SZ_KV;    // V^T             (SZ_KV)
        bf16* ao_ws = vt_ws + SZ_KV;        // attn out        (SZ_D)

        // cast x and wq together, then Q-proj
        cast2_kernel<<<2 * (SZ_D / 2048), blk, 0, stream>>>(x, xb, wq, wbuf,
                                                            (int)(SZ_D / 2048));
        gemm_nt_256<bf16><<<dim3(16, 16), dim3(512), 0, stream>>>(xb, wbuf, q_ws, 4096, 4096, 4096);

        // cast wk+wv stacked (rows 0-1023 = wk, 1024-2047 = wv), merged KV-proj
        cast2_kernel<<<2 * (SZ_KV / 2048), blk, 0, stream>>>(wk, wbuf, wv, wbuf + SZ_KV,
                                                             (int)(SZ_KV / 2048));
        gemm_nt_fast<bf16><<<dim3(16, 32), blk, 0, stream>>>(xb, wbuf, kv_ws, 4096, 2048, 4096);

        // fused K-RoPE + V-transpose (Q-rope fused into attn)
        rope_tr_kernel<<<(B_ * S_ * KVH_ * 64) / 256 + 1024, blk, 0, stream>>>(
            kv_ws, vt_ws, cosb, sinb);

        attn_kernel<<<dim3(32, 16, 2), dim3(512), 0, stream>>>(
            q_ws, kv_ws, vt_ws, ao_ws, cosb, sinb);

        cast_kernel<<<SZ_D / 2048, blk, 0, stream>>>(wo, wbuf);
        gemm_nt_256<float><<<dim3(16, 16), dim3(512), 0, stream>>>(ao_ws, wbuf, out, 4096, 4096, 4096);
    } else {
        // fallback: slow GEMMs straight from f32 inputs (fits in ~92 MB ws)
        bf16* q_ws  = (bf16*)d_ws;
        bf16* kv_ws = q_ws  + SZ_D;
        bf16* vt_ws = kv_ws + 2 * SZ_KV;
        bf16* ao_ws = vt_ws + SZ_KV;

        gemm_nt<float, float, bf16><<<dim3(32, 32), blk, 0, stream>>>(x, wq, q_ws, 4096, 4096, 4096, 4096);
        gemm_nt<float, float, bf16><<<dim3(8, 32),  blk, 0, stream>>>(x, wk, kv_ws, 4096, 1024, 4096, KVSTR);
        gemm_nt<float, float, bf16><<<dim3(8, 32),  blk, 0, stream>>>(x, wv, kv_ws + 1024, 4096, 1024, 4096, KVSTR);

        rope_tr_kernel<<<(B_ * S_ * KVH_ * 64) / 256 + 1024, blk, 0, stream>>>(
            kv_ws, vt_ws, cosb, sinb);

        attn_kernel<<<dim3(32, 16, 2), dim3(512), 0, stream>>>(
            q_ws, kv_ws, vt_ws, ao_ws, cosb, sinb);

        gemm_nt<bf16, float, float><<<dim3(32, 32), blk, 0, stream>>>(ao_ws, wo, out, 4096, 4096, 4096, 4096);
    }
}